// Round 7
// baseline (279.223 us; speedup 1.0000x reference)
//
#include <hip/hip_runtime.h>

// FacetCrossAttention: B=8, P=512, K=16, H=16, D=1024, DH=64
// Factorized pipeline (bf16 MFMA, f32 accum):
//   Wt[b,e,h] = sum_dh wk[e,h*64+dh] Q[b,h*64+dh];  c[b,h] = bk . Q_h
//   scores[h,k] = (G[k,:].Wt[:,h] + c)/8 + log(conf)   (per b,p; MFMA)
//   alpha = sparsemax_k (shuffle bitonic sort + scan + ballot)
//   Gbar[h,:] = sum_k alpha[h,k] G[k,:]   (MFMA; A = G^T via LDS gathers)
//   AV = Gbar_h @ wv_h + bv  (barrier-free direct-global MFMA GEMM)
//   y = AV @ wo + bo (barrier-free direct-global MFMA GEMM); LayerNorm in place.

typedef float f32x4 __attribute__((ext_vector_type(4)));
typedef short s16x4 __attribute__((ext_vector_type(4)));
typedef short s16x8 __attribute__((ext_vector_type(8)));

__device__ __forceinline__ unsigned short f2bf(float f) {
  unsigned u = __builtin_bit_cast(unsigned, f);
  u = (u + 0x7FFFu + ((u >> 16) & 1u)) >> 16;
  return (unsigned short)u;
}

__device__ __forceinline__ s16x8 pack8(s16x4 lo, s16x4 hi) {
  s16x8 r;
  r[0] = lo[0]; r[1] = lo[1]; r[2] = lo[2]; r[3] = lo[3];
  r[4] = hi[0]; r[5] = hi[1]; r[6] = hi[2]; r[7] = hi[3];
  return r;
}

// ---- K0: transpose wv and wo (f32 1024x1024) into bf16 [col][k] layouts ----
__global__ __launch_bounds__(256) void k_trans(
    const float* __restrict__ wv, const float* __restrict__ wo,
    unsigned short* __restrict__ wvt, unsigned short* __restrict__ wot) {
  __shared__ float ts[64][65];
  int bid = blockIdx.x;
  const float* src = (bid < 256) ? wv : wo;
  unsigned short* dst = (bid < 256) ? wvt : wot;
  int tile = bid & 255;
  int er = (tile >> 4) << 6;
  int cb = (tile & 15) << 6;
  int t = threadIdx.x;
  int r = t >> 2, c0 = (t & 3) << 4;
#pragma unroll
  for (int j = 0; j < 16; j += 4) {
    f32x4 v = *(const f32x4*)&src[(long)(er + r) * 1024 + cb + c0 + j];
    ts[r][c0 + j + 0] = v[0];
    ts[r][c0 + j + 1] = v[1];
    ts[r][c0 + j + 2] = v[2];
    ts[r][c0 + j + 3] = v[3];
  }
  __syncthreads();
  s16x8 o0, o1;
#pragma unroll
  for (int j = 0; j < 8; ++j) o0[j] = (short)f2bf(ts[c0 + j][r]);
#pragma unroll
  for (int j = 0; j < 8; ++j) o1[j] = (short)f2bf(ts[c0 + 8 + j][r]);
  long ob = (long)(cb + r) * 1024 + er + c0;
  *(s16x8*)&dst[ob] = o0;
  *(s16x8*)&dst[ob + 8] = o1;
}

// ---- K1a: qpart[b][eq][d] = sum_{e in eq} cq[b,e] wq[e,d]  (wq read once) ----
__global__ __launch_bounds__(256) void k_qpart(
    const float* __restrict__ cq, const float* __restrict__ wq,
    float* __restrict__ qpart) {
  int eq = blockIdx.x, t = threadIdx.x;
  int d0 = t << 2;
  f32x4 acc[8] = {};
  for (int i = 0; i < 64; ++i) {
    int e = (eq << 6) + i;
    f32x4 w = *(const f32x4*)&wq[(long)e * 1024 + d0];
#pragma unroll
    for (int b = 0; b < 8; ++b) acc[b] += w * cq[(b << 10) + e];
  }
#pragma unroll
  for (int b = 0; b < 8; ++b)
    *(f32x4*)&qpart[(long)((b << 4) + eq) * 1024 + d0] = acc[b];
}

// ---- K1b: Wt[b][h][e] (bf16) and c[b][h] ----
__global__ __launch_bounds__(256) void k_wtilde(
    const float* __restrict__ wk, const float* __restrict__ bk,
    const float* __restrict__ bq, const float* __restrict__ qpart,
    unsigned short* __restrict__ wt, float* __restrict__ cvec) {
  __shared__ float Qs[16][68];
  int et = blockIdx.x, b = blockIdx.y, t = threadIdx.x;
#pragma unroll
  for (int j = 0; j < 4; ++j) {
    int d = t + (j << 8);
    float s = bq[d];
    for (int q = 0; q < 16; ++q) s += qpart[(long)((b << 4) + q) * 1024 + d];
    Qs[d >> 6][d & 63] = s;
  }
  __syncthreads();
  int h = t & 15, el = t >> 4;
#pragma unroll
  for (int ii = 0; ii < 8; ++ii) {
    int e = (et << 7) + (ii << 4) + el;
    const float* wr = &wk[(long)e * 1024 + (h << 6)];
    float s = 0.f;
#pragma unroll
    for (int d = 0; d < 64; d += 4) {
      f32x4 w = *(const f32x4*)&wr[d];
      s += w[0] * Qs[h][d] + w[1] * Qs[h][d + 1] + w[2] * Qs[h][d + 2] + w[3] * Qs[h][d + 3];
    }
    wt[(long)((b << 4) + h) * 1024 + e] = f2bf(s);
  }
  if (et == 0 && t < 16) {
    float s = 0.f;
    for (int d = 0; d < 64; ++d) s += bk[(t << 6) + d] * Qs[t][d];
    cvec[(b << 4) + t] = s;
  }
}

// ---- K2: per (b,p): scores -> sparsemax -> Gbar (h-major global) ----
// ~37 KB LDS; natural occupancy (no min-waves VGPR cap).
#define GSTR 1028
__global__ __launch_bounds__(256) void k_scores(
    const float* __restrict__ G, const float* __restrict__ conf,
    const unsigned short* __restrict__ wt, const float* __restrict__ cvec,
    float* __restrict__ alpha_out, unsigned short* __restrict__ gbar,
    int b0, int hstride) {
  __shared__ short Gs[16 * GSTR];  // [k][e] row-major
  __shared__ short As[16 * 32];    // alpha bf16, zero-padded kf in [16,32)
  __shared__ float ps[1024];
  __shared__ float lc[16];

  int t = threadIdx.x;
  int lane = t & 63, w = t >> 6;
  int l15 = lane & 15, g4 = lane >> 4;
  int bp = blockIdx.x;
  long gbp = (long)b0 * 512 + bp;
  int b = (int)(gbp >> 9);
  const float* Grow = G + gbp * 16384;
  const unsigned short* wtb = wt + (long)b * 16384;

  // load G -> Gs (bf16): thread t owns e = 4t..4t+3
#pragma unroll 4
  for (int k = 0; k < 16; ++k) {
    f32x4 g = *(const f32x4*)&Grow[(k << 10) + (t << 2)];
    s16x4 h4;
    h4[0] = (short)f2bf(g[0]); h4[1] = (short)f2bf(g[1]);
    h4[2] = (short)f2bf(g[2]); h4[3] = (short)f2bf(g[3]);
    *(s16x4*)&Gs[k * GSTR + (t << 2)] = h4;
  }
  if (t < 16) lc[t] = logf(fmaxf(conf[gbp * 16 + t], 1e-6f));
  __syncthreads();

  // phase 1: scores^T[h][kf] partials; A = Wt rows (direct global), B = Gs rows
  f32x4 sc = {0.f, 0.f, 0.f, 0.f};
#pragma unroll
  for (int i = 0; i < 8; ++i) {
    int e0 = (w << 8) + (i << 5) + (g4 << 3);
    s16x8 af = *(const s16x8*)&wtb[l15 * 1024 + e0];
    int off = l15 * GSTR + e0;
    s16x8 bf = pack8(*(const s16x4*)&Gs[off], *(const s16x4*)&Gs[off + 4]);
    sc = __builtin_amdgcn_mfma_f32_16x16x32_bf16(af, bf, sc, 0, 0, 0);
  }
#pragma unroll
  for (int r = 0; r < 4; ++r)
    ps[(w << 8) + ((g4 << 2) + r) * 16 + l15] = sc[r];
  __syncthreads();

  // sparsemax: thread (h = t>>4, k = t&15); 16-lane groups via shuffles
  {
    int h = t >> 4, k = t & 15;
    float z = (ps[h * 16 + k] + ps[256 + h * 16 + k] + ps[512 + h * 16 + k] +
               ps[768 + h * 16 + k] + cvec[b * 16 + h]) * 0.125f + lc[k];
    float v = z;
#pragma unroll
    for (int kk = 2; kk <= 16; kk <<= 1) {
#pragma unroll
      for (int j = kk >> 1; j > 0; j >>= 1) {
        float o = __shfl_xor(v, j, 64);
        bool dirDesc = ((l15 & kk) == 0);
        bool takeMax = (((l15 & j) == 0) == dirDesc);
        v = takeMax ? fmaxf(v, o) : fminf(v, o);
      }
    }
    float cs = v;
#pragma unroll
    for (int d = 1; d < 16; d <<= 1) {
      float o = __shfl_up(cs, (unsigned)d, 16);
      if (l15 >= d) cs += o;
    }
    bool sup = (1.0f + (float)(l15 + 1) * v) > cs;
    unsigned long long m = __ballot(sup);
    int gb16 = lane & 48;
    int ksup = (int)__popcll((m >> gb16) & 0xFFFFull);
    float csk = __shfl(cs, ksup - 1, 16);
    float tau = (csk - 1.0f) / (float)ksup;
    float a = fmaxf(z - tau, 0.0f);
    alpha_out[((gbp << 4) + h) * 16 + k] = a;
    As[(h << 5) + k] = (short)f2bf(a);
    As[(h << 5) + 16 + k] = 0;
  }
  __syncthreads();

  // phase 2: Gbar^T: A = G^T (scalar LDS gathers), B = alpha.
  // kf0 = (g4&1)*8: lanes g4>=2 re-read real rows kf 0..15 (finite, in-bounds);
  // their products hit the exact-zero alpha pad.
  s16x8 ab = *(const s16x8*)&As[(l15 << 5) + (g4 << 3)];
  int kf0 = (g4 & 1) << 3;
#pragma unroll 4
  for (int i = 0; i < 16; ++i) {
    int ebase = ((w << 4) + i) << 4;
    int eA = ebase + l15;
    s16x8 aa;
#pragma unroll
    for (int j = 0; j < 8; ++j) aa[j] = Gs[(kf0 + j) * GSTR + eA];
    f32x4 d2 = __builtin_amdgcn_mfma_f32_16x16x32_bf16(
        aa, ab, (f32x4){0.f, 0.f, 0.f, 0.f}, 0, 0, 0);
    s16x4 o4;
    o4[0] = (short)f2bf(d2[0]); o4[1] = (short)f2bf(d2[1]);
    o4[2] = (short)f2bf(d2[2]); o4[3] = (short)f2bf(d2[3]);
    // D: col = h = l15, rows = e = ebase + g4*4 + r; store into [h][bp][e]
    *(s16x4*)&gbar[(long)l15 * hstride + (long)bp * 1024 + ebase + (g4 << 2)] = o4;
  }
}

// ---- K3: AV = Gbar_h @ wvt_h + bv.  Barrier-free, LDS-free: MFMA fragments
// loaded directly from global (gbar L3-hot, wvt L2-hot). 128x64 tile/block.
__global__ __launch_bounds__(256) void k_av(
    const unsigned short* __restrict__ gbar, const unsigned short* __restrict__ wvt,
    const float* __restrict__ bv, unsigned short* __restrict__ av,
    int b0, int hstride) {
  int t = threadIdx.x;
  int lane = t & 63, w = t >> 6;
  int l15 = lane & 15, g4 = lane >> 4;
  int wm = w >> 1, wn = w & 1;
  int tile = blockIdx.x, h = blockIdx.y;
  const unsigned short* Ab = gbar + (long)h * hstride + (long)tile * 128 * 1024;
  const unsigned short* Bb = wvt + (long)(h << 6) * 1024;
  const unsigned short* Ap[4];
  const unsigned short* Bp[2];
#pragma unroll
  for (int im = 0; im < 4; ++im)
    Ap[im] = Ab + (long)(wm * 64 + im * 16 + l15) * 1024 + (g4 << 3);
#pragma unroll
  for (int in = 0; in < 2; ++in)
    Bp[in] = Bb + (long)(wn * 32 + in * 16 + l15) * 1024 + (g4 << 3);
  f32x4 acc[4][2] = {};
#pragma unroll 2
  for (int kb = 0; kb < 32; ++kb) {
    s16x8 af[4], bf[2];
#pragma unroll
    for (int im = 0; im < 4; ++im) af[im] = *(const s16x8*)&Ap[im][kb << 5];
#pragma unroll
    for (int in = 0; in < 2; ++in) bf[in] = *(const s16x8*)&Bp[in][kb << 5];
#pragma unroll
    for (int im = 0; im < 4; ++im)
#pragma unroll
      for (int in = 0; in < 2; ++in)
        acc[im][in] = __builtin_amdgcn_mfma_f32_16x16x32_bf16(af[im], bf[in], acc[im][in], 0, 0, 0);
  }
  long grow0 = (long)b0 * 512 + (long)tile * 128 + wm * 64 + (g4 << 2);
#pragma unroll
  for (int in = 0; in < 2; ++in) {
    int colg = (h << 6) + wn * 32 + in * 16 + l15;
    float bvv = bv[colg];
#pragma unroll
    for (int im = 0; im < 4; ++im) {
      long rowg = grow0 + im * 16;
#pragma unroll
      for (int r = 0; r < 4; ++r)
        av[(rowg + r) * 1024 + colg] = f2bf(acc[im][in][r] + bvv);
    }
  }
}

// ---- K4: y = AV @ wo + bo.  Barrier-free, LDS-free direct-global MFMA.
// 64x128 tile/block, grid (64, 8) = 512 blocks (2/CU).
__global__ __launch_bounds__(256) void k_out(
    const unsigned short* __restrict__ av, const unsigned short* __restrict__ wot,
    const float* __restrict__ bo, float* __restrict__ y) {
  int mt = blockIdx.x, nt = blockIdx.y, t = threadIdx.x;
  int lane = t & 63, w = t >> 6;
  int l15 = lane & 15, g4 = lane >> 4;
  const unsigned short* Ap[4];
  const unsigned short* Bp[2];
#pragma unroll
  for (int im = 0; im < 4; ++im)
    Ap[im] = av + (long)(mt * 64 + im * 16 + l15) * 1024 + (g4 << 3);
#pragma unroll
  for (int in = 0; in < 2; ++in)
    Bp[in] = wot + (long)(nt * 128 + w * 32 + in * 16 + l15) * 1024 + (g4 << 3);
  f32x4 acc[4][2] = {};
#pragma unroll 2
  for (int kb = 0; kb < 32; ++kb) {
    s16x8 af[4], bf[2];
#pragma unroll
    for (int im = 0; im < 4; ++im) af[im] = *(const s16x8*)&Ap[im][kb << 5];
#pragma unroll
    for (int in = 0; in < 2; ++in) bf[in] = *(const s16x8*)&Bp[in][kb << 5];
#pragma unroll
    for (int im = 0; im < 4; ++im)
#pragma unroll
      for (int in = 0; in < 2; ++in)
        acc[im][in] = __builtin_amdgcn_mfma_f32_16x16x32_bf16(af[im], bf[in], acc[im][in], 0, 0, 0);
  }
#pragma unroll
  for (int in = 0; in < 2; ++in) {
    int colg = nt * 128 + w * 32 + in * 16 + l15;
    float bov = bo[colg];
#pragma unroll
    for (int im = 0; im < 4; ++im) {
      long rowg = (long)mt * 64 + im * 16 + (g4 << 2);
#pragma unroll
      for (int r = 0; r < 4; ++r)
        y[(rowg + r) * 1024 + colg] = acc[im][in][r] + bov;
    }
  }
}

// ---- K5: in-place LayerNorm over last dim ----
__global__ __launch_bounds__(256) void k_ln(
    float* __restrict__ y, const float* __restrict__ gamma,
    const float* __restrict__ beta) {
  int row = (blockIdx.x << 2) + (threadIdx.x >> 6);
  int lane = threadIdx.x & 63;
  float* yr = y + ((long)row << 10);
  f32x4 v[4];
  float s = 0.f, s2 = 0.f;
#pragma unroll
  for (int j = 0; j < 4; ++j) {
    v[j] = *(const f32x4*)&yr[(lane << 2) + (j << 8)];
#pragma unroll
    for (int q = 0; q < 4; ++q) { s += v[j][q]; s2 += v[j][q] * v[j][q]; }
  }
#pragma unroll
  for (int d = 1; d < 64; d <<= 1) {
    s += __shfl_xor(s, d, 64);
    s2 += __shfl_xor(s2, d, 64);
  }
  float mu = s * (1.0f / 1024.0f);
  float var = s2 * (1.0f / 1024.0f) - mu * mu;
  float rs = rsqrtf(var + 1e-5f);
#pragma unroll
  for (int j = 0; j < 4; ++j) {
    int f0 = (lane << 2) + (j << 8);
    f32x4 gm = *(const f32x4*)&gamma[f0];
    f32x4 bt = *(const f32x4*)&beta[f0];
    f32x4 o;
#pragma unroll
    for (int q = 0; q < 4; ++q) o[q] = (v[j][q] - mu) * rs * gm[q] + bt[q];
    *(f32x4*)&yr[f0] = o;
  }
}

extern "C" void kernel_launch(void* const* d_in, const int* in_sizes, int n_in,
                              void* d_out, int out_size, void* d_ws, size_t ws_size,
                              hipStream_t stream) {
  (void)in_sizes; (void)n_in; (void)out_size;
  const float* cq    = (const float*)d_in[0];
  const float* G     = (const float*)d_in[1];
  const float* conf  = (const float*)d_in[2];
  const float* wq    = (const float*)d_in[3];
  const float* bq    = (const float*)d_in[4];
  const float* wk    = (const float*)d_in[5];
  const float* bk    = (const float*)d_in[6];
  const float* wv    = (const float*)d_in[7];
  const float* bv    = (const float*)d_in[8];
  const float* wo    = (const float*)d_in[9];
  const float* bo    = (const float*)d_in[10];
  const float* gamma = (const float*)d_in[11];
  const float* beta  = (const float*)d_in[12];

  float* y = (float*)d_out;
  float* alpha = y + 4194304;  // out (8*512*1024) then alpha (8*512*16*16)

  char* p = (char*)d_ws;
  float* qpart = (float*)p;                  p += 8L * 16 * 1024 * 4;   // 512KB
  float* cvec  = (float*)p;                  p += 1024;
  unsigned short* wt   = (unsigned short*)p; p += 8L * 16 * 1024 * 2;   // 256KB
  unsigned short* wvt  = (unsigned short*)p; p += 1024L * 1024 * 2;     // 2MB
  unsigned short* wot  = (unsigned short*)p; p += 1024L * 1024 * 2;     // 2MB
  unsigned short* av   = (unsigned short*)p; p += 4096L * 1024 * 2;     // 8MB
  unsigned short* gbar = (unsigned short*)p;
  size_t used = (size_t)(p - (char*)d_ws);
  size_t per_b = 512L * 16 * 1024 * 2;  // 16MB of Gbar per batch
  int nb = 1;
  if (ws_size >= used + 8 * per_b) nb = 8;
  else if (ws_size >= used + 4 * per_b) nb = 4;
  else if (ws_size >= used + 2 * per_b) nb = 2;
  int hstride = nb * 512 * 1024;  // u16 elements per h-plane of gbar

  hipLaunchKernelGGL(k_trans, dim3(512), dim3(256), 0, stream, wv, wo, wvt, wot);
  hipLaunchKernelGGL(k_qpart, dim3(16), dim3(256), 0, stream, cq, wq, qpart);
  hipLaunchKernelGGL(k_wtilde, dim3(8, 8), dim3(256), 0, stream, wk, bk, bq, qpart, wt, cvec);
  for (int c = 0; c < 8; c += nb) {
    hipLaunchKernelGGL(k_scores, dim3(nb * 512), dim3(256), 0, stream,
                       G, conf, wt, cvec, alpha, gbar, c, hstride);
    hipLaunchKernelGGL(k_av, dim3(nb * 4, 16), dim3(256), 0, stream,
                       gbar, wvt, bv, av, c, hstride);
  }
  hipLaunchKernelGGL(k_out, dim3(64, 8), dim3(256), 0, stream, av, wot, bo, y);
  hipLaunchKernelGGL(k_ln, dim3(1024), dim3(256), 0, stream, y, gamma, beta);
}

// Round 8
// 215.525 us; speedup vs baseline: 1.2955x; 1.2955x over previous
//
#include <hip/hip_runtime.h>

// FacetCrossAttention: B=8, P=512, K=16, H=16, D=1024, DH=64
// Factorized pipeline (bf16 MFMA, f32 accum):
//   Wt[b,e,h] = sum_dh wk[e,h*64+dh] Q[b,h*64+dh];  c[b,h] = bk . Q_h
//   scores[h,k] = (G[k,:].Wt[:,h] + c)/8 + log(conf)   (per b,p; MFMA)
//   alpha = sparsemax_k (shuffle bitonic sort + scan + ballot)
//   Gbar[h,:] = sum_k alpha[h,k] G[k,:]   (MFMA; A = G^T via write-side transpose)
//   AV = Gbar_h @ wv_h + bv  (per-h GEMM, h-major gbar, LDS-staged)
//   y = AV @ wo + bo; LayerNorm in place.

typedef float f32x4 __attribute__((ext_vector_type(4)));
typedef short s16x4 __attribute__((ext_vector_type(4)));
typedef short s16x8 __attribute__((ext_vector_type(8)));

__device__ __forceinline__ unsigned short f2bf(float f) {
  unsigned u = __builtin_bit_cast(unsigned, f);
  u = (u + 0x7FFFu + ((u >> 16) & 1u)) >> 16;
  return (unsigned short)u;
}

__device__ __forceinline__ s16x8 pack8(s16x4 lo, s16x4 hi) {
  s16x8 r;
  r[0] = lo[0]; r[1] = lo[1]; r[2] = lo[2]; r[3] = lo[3];
  r[4] = hi[0]; r[5] = hi[1]; r[6] = hi[2]; r[7] = hi[3];
  return r;
}

// ---- K0: fused {transpose wv/wo to bf16 [col][k]} + {qpart, 64-block} ----
__global__ __launch_bounds__(256) void k_transq(
    const float* __restrict__ wv, const float* __restrict__ wo,
    unsigned short* __restrict__ wvt, unsigned short* __restrict__ wot,
    const float* __restrict__ cq, const float* __restrict__ wq,
    float* __restrict__ qpart) {
  int bid = blockIdx.x;
  int t = threadIdx.x;
  if (bid < 512) {
    __shared__ float ts[64][65];
    const float* src = (bid < 256) ? wv : wo;
    unsigned short* dst = (bid < 256) ? wvt : wot;
    int tile = bid & 255;
    int er = (tile >> 4) << 6;
    int cb = (tile & 15) << 6;
    int r = t >> 2, c0 = (t & 3) << 4;
#pragma unroll
    for (int j = 0; j < 16; j += 4) {
      f32x4 v = *(const f32x4*)&src[(long)(er + r) * 1024 + cb + c0 + j];
      ts[r][c0 + j + 0] = v[0];
      ts[r][c0 + j + 1] = v[1];
      ts[r][c0 + j + 2] = v[2];
      ts[r][c0 + j + 3] = v[3];
    }
    __syncthreads();
    s16x8 o0, o1;
#pragma unroll
    for (int j = 0; j < 8; ++j) o0[j] = (short)f2bf(ts[c0 + j][r]);
#pragma unroll
    for (int j = 0; j < 8; ++j) o1[j] = (short)f2bf(ts[c0 + 8 + j][r]);
    long ob = (long)(cb + r) * 1024 + er + c0;
    *(s16x8*)&dst[ob] = o0;
    *(s16x8*)&dst[ob + 8] = o1;
  } else {
    // qpart[b][eq][d] = sum_{e in eq-chunk} cq[b,e] wq[e,d]
    // 64 blocks: (eq, d-quarter); coalesced scalar-f32 loads.
    int idx = bid - 512;
    int eq = idx >> 2, dq = idx & 3;
    int d = (dq << 8) + t;
    float acc[8] = {};
    for (int i = 0; i < 64; ++i) {
      int e = (eq << 6) + i;
      float w = wq[(long)e * 1024 + d];
#pragma unroll
      for (int b = 0; b < 8; ++b) acc[b] += w * cq[(b << 10) + e];
    }
#pragma unroll
    for (int b = 0; b < 8; ++b)
      qpart[(long)((b << 4) + eq) * 1024 + d] = acc[b];
  }
}

// ---- K1: Wt[b][h][e] (bf16) and c[b][h] ----
__global__ __launch_bounds__(256) void k_wtilde(
    const float* __restrict__ wk, const float* __restrict__ bk,
    const float* __restrict__ bq, const float* __restrict__ qpart,
    unsigned short* __restrict__ wt, float* __restrict__ cvec) {
  __shared__ float Qs[16][68];
  int et = blockIdx.x, b = blockIdx.y, t = threadIdx.x;
  {
    // vectorized Q assembly: 16 independent f32x4 loads per thread
    int d0 = t << 2;
    f32x4 s4 = *(const f32x4*)&bq[d0];
#pragma unroll
    for (int q = 0; q < 16; ++q)
      s4 += *(const f32x4*)&qpart[(long)((b << 4) + q) * 1024 + d0];
    *(f32x4*)&Qs[d0 >> 6][d0 & 63] = s4;
  }
  __syncthreads();
  int h = t & 15, el = t >> 4;
#pragma unroll
  for (int ii = 0; ii < 8; ++ii) {
    int e = (et << 7) + (ii << 4) + el;
    const float* wr = &wk[(long)e * 1024 + (h << 6)];
    float s = 0.f;
#pragma unroll
    for (int d = 0; d < 64; d += 4) {
      f32x4 w = *(const f32x4*)&wr[d];
      s += w[0] * Qs[h][d] + w[1] * Qs[h][d + 1] + w[2] * Qs[h][d + 2] + w[3] * Qs[h][d + 3];
    }
    wt[(long)((b << 4) + h) * 1024 + e] = f2bf(s);
  }
  if (et == 0 && t < 16) {
    float s = 0.f;
    for (int d = 0; d < 64; ++d) s += bk[(t << 6) + d] * Qs[t][d];
    cvec[(b << 4) + t] = s;
  }
}

// ---- K2: per (b,p): scores -> sparsemax -> Gbar (h-major global) ----
#define GSTR 1028
#define TSTR 20
__global__ __launch_bounds__(256, 2) void k_scores(
    const float* __restrict__ G, const float* __restrict__ conf,
    const unsigned short* __restrict__ wt, const float* __restrict__ cvec,
    float* __restrict__ alpha_out, unsigned short* __restrict__ gbar,
    int b0, int hstride) {
  __shared__ short Gs[16 * GSTR];    // [k][e] row-major (phase 1 B-operand)
  __shared__ short Gt[1024 * TSTR];  // [e][kf] transposed (phase 2 A-operand)
  __shared__ short As[16 * 32];      // alpha bf16, zero-padded kf in [16,32)
  __shared__ float ps[1024];
  __shared__ float lc[16];

  int t = threadIdx.x;
  int lane = t & 63, w = t >> 6;
  int l15 = lane & 15, g4 = lane >> 4;
  int bp = blockIdx.x;
  long gbp = (long)b0 * 512 + bp;
  int b = (int)(gbp >> 9);
  const float* Grow = G + gbp * 16384;
  const unsigned short* wtb = wt + (long)b * 16384;

  // load G: thread t owns e = 4t..4t+3; write Gs [k][e] and Gt [e][kf]
#pragma unroll
  for (int half = 0; half < 2; ++half) {
    s16x4 col[8];
#pragma unroll
    for (int j = 0; j < 8; ++j) {
      int k = (half << 3) + j;
      f32x4 g = *(const f32x4*)&Grow[(k << 10) + (t << 2)];
      s16x4 h4;
      h4[0] = (short)f2bf(g[0]); h4[1] = (short)f2bf(g[1]);
      h4[2] = (short)f2bf(g[2]); h4[3] = (short)f2bf(g[3]);
      *(s16x4*)&Gs[k * GSTR + (t << 2)] = h4;
      col[j] = h4;
    }
#pragma unroll
    for (int q = 0; q < 4; ++q) {
      int e = (t << 2) + q;
      s16x4 lo, hi;
      lo[0] = col[0][q]; lo[1] = col[1][q]; lo[2] = col[2][q]; lo[3] = col[3][q];
      hi[0] = col[4][q]; hi[1] = col[5][q]; hi[2] = col[6][q]; hi[3] = col[7][q];
      *(s16x4*)&Gt[e * TSTR + (half << 3)] = lo;
      *(s16x4*)&Gt[e * TSTR + (half << 3) + 4] = hi;
    }
  }
  if (t < 16) lc[t] = logf(fmaxf(conf[gbp * 16 + t], 1e-6f));
  __syncthreads();

  // phase 1: scores^T[h][kf] partials; A = Wt rows (direct global), B = Gs rows
  f32x4 sc = {0.f, 0.f, 0.f, 0.f};
#pragma unroll
  for (int i = 0; i < 8; ++i) {
    int e0 = (w << 8) + (i << 5) + (g4 << 3);
    s16x8 af = *(const s16x8*)&wtb[l15 * 1024 + e0];
    int off = l15 * GSTR + e0;
    s16x8 bf = pack8(*(const s16x4*)&Gs[off], *(const s16x4*)&Gs[off + 4]);
    sc = __builtin_amdgcn_mfma_f32_16x16x32_bf16(af, bf, sc, 0, 0, 0);
  }
#pragma unroll
  for (int r = 0; r < 4; ++r)
    ps[(w << 8) + ((g4 << 2) + r) * 16 + l15] = sc[r];
  __syncthreads();

  // sparsemax: thread (h = t>>4, k = t&15); 16-lane groups via shuffles
  {
    int h = t >> 4, k = t & 15;
    float z = (ps[h * 16 + k] + ps[256 + h * 16 + k] + ps[512 + h * 16 + k] +
               ps[768 + h * 16 + k] + cvec[b * 16 + h]) * 0.125f + lc[k];
    float v = z;
#pragma unroll
    for (int kk = 2; kk <= 16; kk <<= 1) {
#pragma unroll
      for (int j = kk >> 1; j > 0; j >>= 1) {
        float o = __shfl_xor(v, j, 64);
        bool dirDesc = ((l15 & kk) == 0);
        bool takeMax = (((l15 & j) == 0) == dirDesc);
        v = takeMax ? fmaxf(v, o) : fminf(v, o);
      }
    }
    float cs = v;
#pragma unroll
    for (int d = 1; d < 16; d <<= 1) {
      float o = __shfl_up(cs, (unsigned)d, 16);
      if (l15 >= d) cs += o;
    }
    bool sup = (1.0f + (float)(l15 + 1) * v) > cs;
    unsigned long long m = __ballot(sup);
    int gb16 = lane & 48;
    int ksup = (int)__popcll((m >> gb16) & 0xFFFFull);
    float csk = __shfl(cs, ksup - 1, 16);
    float tau = (csk - 1.0f) / (float)ksup;
    float a = fmaxf(z - tau, 0.0f);
    alpha_out[((gbp << 4) + h) * 16 + k] = a;
    As[(h << 5) + k] = (short)f2bf(a);
    As[(h << 5) + 16 + k] = 0;
  }
  __syncthreads();

  // phase 2: Gbar^T: A = Gt rows (e-major, kf contiguous), B = alpha.
  // g4>=2 lanes re-read kf 0..15 (finite); annihilated by exact-zero alpha pad.
  s16x8 ab = *(const s16x8*)&As[(l15 << 5) + (g4 << 3)];
#pragma unroll 4
  for (int i = 0; i < 16; ++i) {
    int ebase = ((w << 4) + i) << 4;
    int ro = (ebase + l15) * TSTR + ((g4 & 1) << 3);
    s16x8 aa = pack8(*(const s16x4*)&Gt[ro], *(const s16x4*)&Gt[ro + 4]);
    f32x4 d2 = __builtin_amdgcn_mfma_f32_16x16x32_bf16(
        aa, ab, (f32x4){0.f, 0.f, 0.f, 0.f}, 0, 0, 0);
    s16x4 o4;
    o4[0] = (short)f2bf(d2[0]); o4[1] = (short)f2bf(d2[1]);
    o4[2] = (short)f2bf(d2[2]); o4[3] = (short)f2bf(d2[3]);
    // D: col = h = l15, rows = e = ebase + g4*4 + r; store into [h][bp][e]
    *(s16x4*)&gbar[(long)l15 * hstride + (long)bp * 1024 + ebase + (g4 << 2)] = o4;
  }
}

// ---- K3: AV[bp, h*64+c] = Gbar_h[bp,:] @ wvt[h*64+c,:] + bv (128x64 tile) ----
__global__ __launch_bounds__(256) void k_av(
    const unsigned short* __restrict__ gbar, const unsigned short* __restrict__ wvt,
    const float* __restrict__ bv, unsigned short* __restrict__ av,
    int b0, int hstride) {
  __shared__ short Asm[128 * 40];
  __shared__ short Bsm[64 * 40];
  int t = threadIdx.x;
  int lane = t & 63, w = t >> 6;
  int l15 = lane & 15, g4 = lane >> 4;
  int wm = w >> 1, wn = w & 1;
  int tile = blockIdx.x, h = blockIdx.y;
  const unsigned short* Ab = gbar + (long)h * hstride + (long)tile * 128 * 1024;
  const unsigned short* Bb = wvt + (long)(h << 6) * 1024;
  int ar = t >> 1, ac = (t & 1) << 4;
  int br = t >> 2, bc = (t & 3) << 3;
  const unsigned short* Arp = Ab + (long)ar * 1024 + ac;
  const unsigned short* Brp = Bb + (long)br * 1024 + bc;
  s16x8 a0 = *(const s16x8*)&Arp[0];
  s16x8 a1 = *(const s16x8*)&Arp[8];
  s16x8 b8 = *(const s16x8*)&Brp[0];
  f32x4 acc[4][2] = {};
  for (int kb = 0; kb < 32; ++kb) {
    __syncthreads();
    short* pa = &Asm[ar * 40 + ac];
    *(s16x8*)pa = a0; *(s16x8*)(pa + 8) = a1;
    *(s16x8*)&Bsm[br * 40 + bc] = b8;
    if (kb + 1 < 32) {
      a0 = *(const s16x8*)&Arp[((kb + 1) << 5)];
      a1 = *(const s16x8*)&Arp[((kb + 1) << 5) + 8];
      b8 = *(const s16x8*)&Brp[((kb + 1) << 5)];
    }
    __syncthreads();
    s16x8 afr[4], bfr[2];
#pragma unroll
    for (int im = 0; im < 4; ++im)
      afr[im] = *(const s16x8*)&Asm[(wm * 64 + im * 16 + l15) * 40 + (g4 << 3)];
#pragma unroll
    for (int in = 0; in < 2; ++in)
      bfr[in] = *(const s16x8*)&Bsm[(wn * 32 + in * 16 + l15) * 40 + (g4 << 3)];
#pragma unroll
    for (int im = 0; im < 4; ++im)
#pragma unroll
      for (int in = 0; in < 2; ++in)
        acc[im][in] = __builtin_amdgcn_mfma_f32_16x16x32_bf16(afr[im], bfr[in], acc[im][in], 0, 0, 0);
  }
  long grow0 = (long)b0 * 512 + (long)tile * 128 + wm * 64 + (g4 << 2);
#pragma unroll
  for (int in = 0; in < 2; ++in) {
    int colg = (h << 6) + wn * 32 + in * 16 + l15;
    float bvv = bv[colg];
#pragma unroll
    for (int im = 0; im < 4; ++im) {
      long rowg = grow0 + im * 16;
#pragma unroll
      for (int r = 0; r < 4; ++r)
        av[(rowg + r) * 1024 + colg] = f2bf(acc[im][in][r] + bvv);
    }
  }
}

// ---- K4: y = AV @ wo + bo  (128x128 tiles) ----
__global__ __launch_bounds__(256) void k_out(
    const unsigned short* __restrict__ av, const unsigned short* __restrict__ wot,
    const float* __restrict__ bo, float* __restrict__ y) {
  __shared__ short Asm[128 * 40];
  __shared__ short Bsm[128 * 40];
  int mt = blockIdx.x, nt = blockIdx.y, t = threadIdx.x;
  int lane = t & 63, w = t >> 6;
  int wm = w >> 1, wn = w & 1;
  int l15 = lane & 15, g4 = lane >> 4;
  f32x4 acc[4][4] = {};
  int lr = t >> 1, ls = (t & 1) << 4;
  const unsigned short* Ar = av + ((long)(mt * 128 + lr)) * 1024;
  const unsigned short* Br = wot + ((long)(nt * 128 + lr)) * 1024;
  s16x8 a0 = *(const s16x8*)&Ar[ls];
  s16x8 a1 = *(const s16x8*)&Ar[ls + 8];
  s16x8 b0 = *(const s16x8*)&Br[ls];
  s16x8 b1 = *(const s16x8*)&Br[ls + 8];
  for (int kb = 0; kb < 32; ++kb) {
    __syncthreads();
    short* pa = &Asm[lr * 40 + ls];
    *(s16x8*)pa = a0; *(s16x8*)(pa + 8) = a1;
    short* pb = &Bsm[lr * 40 + ls];
    *(s16x8*)pb = b0; *(s16x8*)(pb + 8) = b1;
    if (kb + 1 < 32) {
      a0 = *(const s16x8*)&Ar[((kb + 1) << 5) + ls];
      a1 = *(const s16x8*)&Ar[((kb + 1) << 5) + ls + 8];
      b0 = *(const s16x8*)&Br[((kb + 1) << 5) + ls];
      b1 = *(const s16x8*)&Br[((kb + 1) << 5) + ls + 8];
    }
    __syncthreads();
    s16x8 afr[4], bfr[4];
#pragma unroll
    for (int im = 0; im < 4; ++im)
      afr[im] = *(const s16x8*)&Asm[(wm * 64 + im * 16 + l15) * 40 + (g4 << 3)];
#pragma unroll
    for (int in = 0; in < 4; ++in)
      bfr[in] = *(const s16x8*)&Bsm[(wn * 64 + in * 16 + l15) * 40 + (g4 << 3)];
#pragma unroll
    for (int im = 0; im < 4; ++im)
#pragma unroll
      for (int in = 0; in < 4; ++in)
        acc[im][in] = __builtin_amdgcn_mfma_f32_16x16x32_bf16(afr[im], bfr[in], acc[im][in], 0, 0, 0);
  }
#pragma unroll
  for (int in = 0; in < 4; ++in) {
    int colg = nt * 128 + wn * 64 + in * 16 + l15;
    float bov = bo[colg];
#pragma unroll
    for (int im = 0; im < 4; ++im) {
      long rowg = mt * 128 + wm * 64 + im * 16 + (g4 << 2);
#pragma unroll
      for (int r = 0; r < 4; ++r)
        y[(rowg + r) * 1024 + colg] = acc[im][in][r] + bov;
    }
  }
}

// ---- K5: in-place LayerNorm over last dim ----
__global__ __launch_bounds__(256) void k_ln(
    float* __restrict__ y, const float* __restrict__ gamma,
    const float* __restrict__ beta) {
  int row = (blockIdx.x << 2) + (threadIdx.x >> 6);
  int lane = threadIdx.x & 63;
  float* yr = y + ((long)row << 10);
  f32x4 v[4];
  float s = 0.f, s2 = 0.f;
#pragma unroll
  for (int j = 0; j < 4; ++j) {
    v[j] = *(const f32x4*)&yr[(lane << 2) + (j << 8)];
#pragma unroll
    for (int q = 0; q < 4; ++q) { s += v[j][q]; s2 += v[j][q] * v[j][q]; }
  }
#pragma unroll
  for (int d = 1; d < 64; d <<= 1) {
    s += __shfl_xor(s, d, 64);
    s2 += __shfl_xor(s2, d, 64);
  }
  float mu = s * (1.0f / 1024.0f);
  float var = s2 * (1.0f / 1024.0f) - mu * mu;
  float rs = rsqrtf(var + 1e-5f);
#pragma unroll
  for (int j = 0; j < 4; ++j) {
    int f0 = (lane << 2) + (j << 8);
    f32x4 gm = *(const f32x4*)&gamma[f0];
    f32x4 bt = *(const f32x4*)&beta[f0];
    f32x4 o;
#pragma unroll
    for (int q = 0; q < 4; ++q) o[q] = (v[j][q] - mu) * rs * gm[q] + bt[q];
    *(f32x4*)&yr[f0] = o;
  }
}

extern "C" void kernel_launch(void* const* d_in, const int* in_sizes, int n_in,
                              void* d_out, int out_size, void* d_ws, size_t ws_size,
                              hipStream_t stream) {
  (void)in_sizes; (void)n_in; (void)out_size;
  const float* cq    = (const float*)d_in[0];
  const float* G     = (const float*)d_in[1];
  const float* conf  = (const float*)d_in[2];
  const float* wq    = (const float*)d_in[3];
  const float* bq    = (const float*)d_in[4];
  const float* wk    = (const float*)d_in[5];
  const float* bk    = (const float*)d_in[6];
  const float* wv    = (const float*)d_in[7];
  const float* bv    = (const float*)d_in[8];
  const float* wo    = (const float*)d_in[9];
  const float* bo    = (const float*)d_in[10];
  const float* gamma = (const float*)d_in[11];
  const float* beta  = (const float*)d_in[12];

  float* y = (float*)d_out;
  float* alpha = y + 4194304;  // out (8*512*1024) then alpha (8*512*16*16)

  char* p = (char*)d_ws;
  float* qpart = (float*)p;                  p += 8L * 16 * 1024 * 4;   // 512KB
  float* cvec  = (float*)p;                  p += 1024;
  unsigned short* wt   = (unsigned short*)p; p += 8L * 16 * 1024 * 2;   // 256KB
  unsigned short* wvt  = (unsigned short*)p; p += 1024L * 1024 * 2;     // 2MB
  unsigned short* wot  = (unsigned short*)p; p += 1024L * 1024 * 2;     // 2MB
  unsigned short* av   = (unsigned short*)p; p += 4096L * 1024 * 2;     // 8MB
  unsigned short* gbar = (unsigned short*)p;
  size_t used = (size_t)(p - (char*)d_ws);
  size_t per_b = 512L * 16 * 1024 * 2;  // 16MB of Gbar per batch
  int nb = 1;
  if (ws_size >= used + 8 * per_b) nb = 8;
  else if (ws_size >= used + 4 * per_b) nb = 4;
  else if (ws_size >= used + 2 * per_b) nb = 2;
  int hstride = nb * 512 * 1024;  // u16 elements per h-plane of gbar

  hipLaunchKernelGGL(k_transq, dim3(576), dim3(256), 0, stream,
                     wv, wo, wvt, wot, cq, wq, qpart);
  hipLaunchKernelGGL(k_wtilde, dim3(8, 8), dim3(256), 0, stream, wk, bk, bq, qpart, wt, cvec);
  for (int c = 0; c < 8; c += nb) {
    hipLaunchKernelGGL(k_scores, dim3(nb * 512), dim3(256), 0, stream,
                       G, conf, wt, cvec, alpha, gbar, c, hstride);
    hipLaunchKernelGGL(k_av, dim3(nb * 4, 16), dim3(256), 0, stream,
                       gbar, wvt, bv, av, c, hstride);
  }
  hipLaunchKernelGGL(k_out, dim3(32, 8), dim3(256), 0, stream, av, wot, bo, y);
  hipLaunchKernelGGL(k_ln, dim3(1024), dim3(256), 0, stream, y, gamma, beta);
}

// Round 9
// 212.955 us; speedup vs baseline: 1.3112x; 1.0121x over previous
//
#include <hip/hip_runtime.h>

// FacetCrossAttention: B=8, P=512, K=16, H=16, D=1024, DH=64
// Factorized pipeline (bf16 MFMA, f32 accum):
//   Wt[b,e,h] = sum_dh wk[e,h*64+dh] Q[b,h*64+dh];  c[b,h] = bk . Q_h
//   scores[h,k] = (G[k,:].Wt[:,h] + c)/8 + log(conf)   (per b,p; MFMA)
//   alpha = sparsemax_k (shuffle bitonic sort + scan + ballot)
//   Gbar[h,:] = sum_k alpha[h,k] G[k,:]   (MFMA; A = G^T via write-side transpose)
//   AV = Gbar_h @ wv_h + bv  (per-h GEMM, h-major gbar, LDS-staged)
//   yb = bf16(AV @ wo + bo); y = LayerNorm(yb) in f32.

typedef float f32x4 __attribute__((ext_vector_type(4)));
typedef short s16x4 __attribute__((ext_vector_type(4)));
typedef short s16x8 __attribute__((ext_vector_type(8)));

__device__ __forceinline__ unsigned short f2bf(float f) {
  unsigned u = __builtin_bit_cast(unsigned, f);
  u = (u + 0x7FFFu + ((u >> 16) & 1u)) >> 16;
  return (unsigned short)u;
}

__device__ __forceinline__ float bf2f(unsigned short u) {
  return __builtin_bit_cast(float, ((unsigned)u) << 16);
}

__device__ __forceinline__ s16x8 pack8(s16x4 lo, s16x4 hi) {
  s16x8 r;
  r[0] = lo[0]; r[1] = lo[1]; r[2] = lo[2]; r[3] = lo[3];
  r[4] = hi[0]; r[5] = hi[1]; r[6] = hi[2]; r[7] = hi[3];
  return r;
}

// ---- K0: fused {transpose wv/wo to bf16 [col][k]} + {qpart, 64-block} ----
__global__ __launch_bounds__(256) void k_transq(
    const float* __restrict__ wv, const float* __restrict__ wo,
    unsigned short* __restrict__ wvt, unsigned short* __restrict__ wot,
    const float* __restrict__ cq, const float* __restrict__ wq,
    float* __restrict__ qpart) {
  int bid = blockIdx.x;
  int t = threadIdx.x;
  if (bid < 512) {
    __shared__ float ts[64][65];
    const float* src = (bid < 256) ? wv : wo;
    unsigned short* dst = (bid < 256) ? wvt : wot;
    int tile = bid & 255;
    int er = (tile >> 4) << 6;
    int cb = (tile & 15) << 6;
    int r = t >> 2, c0 = (t & 3) << 4;
#pragma unroll
    for (int j = 0; j < 16; j += 4) {
      f32x4 v = *(const f32x4*)&src[(long)(er + r) * 1024 + cb + c0 + j];
      ts[r][c0 + j + 0] = v[0];
      ts[r][c0 + j + 1] = v[1];
      ts[r][c0 + j + 2] = v[2];
      ts[r][c0 + j + 3] = v[3];
    }
    __syncthreads();
    s16x8 o0, o1;
#pragma unroll
    for (int j = 0; j < 8; ++j) o0[j] = (short)f2bf(ts[c0 + j][r]);
#pragma unroll
    for (int j = 0; j < 8; ++j) o1[j] = (short)f2bf(ts[c0 + 8 + j][r]);
    long ob = (long)(cb + r) * 1024 + er + c0;
    *(s16x8*)&dst[ob] = o0;
    *(s16x8*)&dst[ob + 8] = o1;
  } else {
    // qpart[b][eq][d] = sum_{e in eq-chunk} cq[b,e] wq[e,d]
    int idx = bid - 512;
    int eq = idx >> 2, dq = idx & 3;
    int d = (dq << 8) + t;
    float acc[8] = {};
    for (int i = 0; i < 64; ++i) {
      int e = (eq << 6) + i;
      float w = wq[(long)e * 1024 + d];
#pragma unroll
      for (int b = 0; b < 8; ++b) acc[b] += w * cq[(b << 10) + e];
    }
#pragma unroll
    for (int b = 0; b < 8; ++b)
      qpart[(long)((b << 4) + eq) * 1024 + d] = acc[b];
  }
}

// ---- K1: Wt[b][h][e] (bf16) and c[b][h] ----
__global__ __launch_bounds__(256) void k_wtilde(
    const float* __restrict__ wk, const float* __restrict__ bk,
    const float* __restrict__ bq, const float* __restrict__ qpart,
    unsigned short* __restrict__ wt, float* __restrict__ cvec) {
  __shared__ float Qs[16][68];
  int et = blockIdx.x, b = blockIdx.y, t = threadIdx.x;
  {
    int d0 = t << 2;
    f32x4 s4 = *(const f32x4*)&bq[d0];
#pragma unroll
    for (int q = 0; q < 16; ++q)
      s4 += *(const f32x4*)&qpart[(long)((b << 4) + q) * 1024 + d0];
    *(f32x4*)&Qs[d0 >> 6][d0 & 63] = s4;
  }
  __syncthreads();
  int h = t & 15, el = t >> 4;
#pragma unroll
  for (int ii = 0; ii < 8; ++ii) {
    int e = (et << 7) + (ii << 4) + el;
    const float* wr = &wk[(long)e * 1024 + (h << 6)];
    float s = 0.f;
#pragma unroll
    for (int d = 0; d < 64; d += 4) {
      f32x4 w = *(const f32x4*)&wr[d];
      s += w[0] * Qs[h][d] + w[1] * Qs[h][d + 1] + w[2] * Qs[h][d + 2] + w[3] * Qs[h][d + 3];
    }
    wt[(long)((b << 4) + h) * 1024 + e] = f2bf(s);
  }
  if (et == 0 && t < 16) {
    float s = 0.f;
    for (int d = 0; d < 64; ++d) s += bk[(t << 6) + d] * Qs[t][d];
    cvec[(b << 4) + t] = s;
  }
}

// ---- K2: per (b,p): scores -> sparsemax -> Gbar (h-major global) ----
#define GSTR 1028
#define TSTR 20
__global__ __launch_bounds__(256, 2) void k_scores(
    const float* __restrict__ G, const float* __restrict__ conf,
    const unsigned short* __restrict__ wt, const float* __restrict__ cvec,
    float* __restrict__ alpha_out, unsigned short* __restrict__ gbar,
    int b0, int hstride) {
  __shared__ short Gs[16 * GSTR];    // [k][e] row-major (phase 1 B-operand)
  __shared__ short Gt[1024 * TSTR];  // [e][kf] transposed (phase 2 A-operand)
  __shared__ short As[16 * 32];      // alpha bf16, zero-padded kf in [16,32)
  __shared__ float ps[1024];
  __shared__ float lc[16];

  int t = threadIdx.x;
  int lane = t & 63, w = t >> 6;
  int l15 = lane & 15, g4 = lane >> 4;
  int bp = blockIdx.x;
  long gbp = (long)b0 * 512 + bp;
  int b = (int)(gbp >> 9);
  const float* Grow = G + gbp * 16384;
  const unsigned short* wtb = wt + (long)b * 16384;

  // load G: thread t owns e = 4t..4t+3; write Gs [k][e] and Gt [e][kf]
#pragma unroll
  for (int half = 0; half < 2; ++half) {
    s16x4 col[8];
#pragma unroll
    for (int j = 0; j < 8; ++j) {
      int k = (half << 3) + j;
      f32x4 g = *(const f32x4*)&Grow[(k << 10) + (t << 2)];
      s16x4 h4;
      h4[0] = (short)f2bf(g[0]); h4[1] = (short)f2bf(g[1]);
      h4[2] = (short)f2bf(g[2]); h4[3] = (short)f2bf(g[3]);
      *(s16x4*)&Gs[k * GSTR + (t << 2)] = h4;
      col[j] = h4;
    }
#pragma unroll
    for (int q = 0; q < 4; ++q) {
      int e = (t << 2) + q;
      s16x4 lo, hi;
      lo[0] = col[0][q]; lo[1] = col[1][q]; lo[2] = col[2][q]; lo[3] = col[3][q];
      hi[0] = col[4][q]; hi[1] = col[5][q]; hi[2] = col[6][q]; hi[3] = col[7][q];
      *(s16x4*)&Gt[e * TSTR + (half << 3)] = lo;
      *(s16x4*)&Gt[e * TSTR + (half << 3) + 4] = hi;
    }
  }
  if (t < 16) lc[t] = logf(fmaxf(conf[gbp * 16 + t], 1e-6f));
  __syncthreads();

  // phase 1: scores^T[h][kf] partials; A = Wt rows (direct global), B = Gs rows
  f32x4 sc = {0.f, 0.f, 0.f, 0.f};
#pragma unroll
  for (int i = 0; i < 8; ++i) {
    int e0 = (w << 8) + (i << 5) + (g4 << 3);
    s16x8 af = *(const s16x8*)&wtb[l15 * 1024 + e0];
    int off = l15 * GSTR + e0;
    s16x8 bf = pack8(*(const s16x4*)&Gs[off], *(const s16x4*)&Gs[off + 4]);
    sc = __builtin_amdgcn_mfma_f32_16x16x32_bf16(af, bf, sc, 0, 0, 0);
  }
#pragma unroll
  for (int r = 0; r < 4; ++r)
    ps[(w << 8) + ((g4 << 2) + r) * 16 + l15] = sc[r];
  __syncthreads();

  // sparsemax: thread (h = t>>4, k = t&15); 16-lane groups via shuffles
  {
    int h = t >> 4, k = t & 15;
    float z = (ps[h * 16 + k] + ps[256 + h * 16 + k] + ps[512 + h * 16 + k] +
               ps[768 + h * 16 + k] + cvec[b * 16 + h]) * 0.125f + lc[k];
    float v = z;
#pragma unroll
    for (int kk = 2; kk <= 16; kk <<= 1) {
#pragma unroll
      for (int j = kk >> 1; j > 0; j >>= 1) {
        float o = __shfl_xor(v, j, 64);
        bool dirDesc = ((l15 & kk) == 0);
        bool takeMax = (((l15 & j) == 0) == dirDesc);
        v = takeMax ? fmaxf(v, o) : fminf(v, o);
      }
    }
    float cs = v;
#pragma unroll
    for (int d = 1; d < 16; d <<= 1) {
      float o = __shfl_up(cs, (unsigned)d, 16);
      if (l15 >= d) cs += o;
    }
    bool sup = (1.0f + (float)(l15 + 1) * v) > cs;
    unsigned long long m = __ballot(sup);
    int gb16 = lane & 48;
    int ksup = (int)__popcll((m >> gb16) & 0xFFFFull);
    float csk = __shfl(cs, ksup - 1, 16);
    float tau = (csk - 1.0f) / (float)ksup;
    float a = fmaxf(z - tau, 0.0f);
    alpha_out[((gbp << 4) + h) * 16 + k] = a;
    As[(h << 5) + k] = (short)f2bf(a);
    As[(h << 5) + 16 + k] = 0;
  }
  __syncthreads();

  // phase 2: Gbar^T: A = Gt rows (e-major, kf contiguous), B = alpha.
  // g4>=2 lanes re-read kf 0..15 (finite); annihilated by exact-zero alpha pad.
  s16x8 ab = *(const s16x8*)&As[(l15 << 5) + (g4 << 3)];
#pragma unroll 4
  for (int i = 0; i < 16; ++i) {
    int ebase = ((w << 4) + i) << 4;
    int ro = (ebase + l15) * TSTR + ((g4 & 1) << 3);
    s16x8 aa = pack8(*(const s16x4*)&Gt[ro], *(const s16x4*)&Gt[ro + 4]);
    f32x4 d2 = __builtin_amdgcn_mfma_f32_16x16x32_bf16(
        aa, ab, (f32x4){0.f, 0.f, 0.f, 0.f}, 0, 0, 0);
    s16x4 o4;
    o4[0] = (short)f2bf(d2[0]); o4[1] = (short)f2bf(d2[1]);
    o4[2] = (short)f2bf(d2[2]); o4[3] = (short)f2bf(d2[3]);
    // D: col = h = l15, rows = e = ebase + g4*4 + r; store into [h][bp][e]
    *(s16x4*)&gbar[(long)l15 * hstride + (long)bp * 1024 + ebase + (g4 << 2)] = o4;
  }
}

// ---- K3: AV[bp, h*64+c] = Gbar_h[bp,:] @ wvt[h*64+c,:] + bv (128x64 tile) ----
__global__ __launch_bounds__(256) void k_av(
    const unsigned short* __restrict__ gbar, const unsigned short* __restrict__ wvt,
    const float* __restrict__ bv, unsigned short* __restrict__ av,
    int b0, int hstride) {
  __shared__ short Asm[128 * 40];
  __shared__ short Bsm[64 * 40];
  int t = threadIdx.x;
  int lane = t & 63, w = t >> 6;
  int l15 = lane & 15, g4 = lane >> 4;
  int wm = w >> 1, wn = w & 1;
  int tile = blockIdx.x, h = blockIdx.y;
  const unsigned short* Ab = gbar + (long)h * hstride + (long)tile * 128 * 1024;
  const unsigned short* Bb = wvt + (long)(h << 6) * 1024;
  int ar = t >> 1, ac = (t & 1) << 4;
  int br = t >> 2, bc = (t & 3) << 3;
  const unsigned short* Arp = Ab + (long)ar * 1024 + ac;
  const unsigned short* Brp = Bb + (long)br * 1024 + bc;
  s16x8 a0 = *(const s16x8*)&Arp[0];
  s16x8 a1 = *(const s16x8*)&Arp[8];
  s16x8 b8 = *(const s16x8*)&Brp[0];
  f32x4 acc[4][2] = {};
  for (int kb = 0; kb < 32; ++kb) {
    __syncthreads();
    short* pa = &Asm[ar * 40 + ac];
    *(s16x8*)pa = a0; *(s16x8*)(pa + 8) = a1;
    *(s16x8*)&Bsm[br * 40 + bc] = b8;
    if (kb + 1 < 32) {
      a0 = *(const s16x8*)&Arp[((kb + 1) << 5)];
      a1 = *(const s16x8*)&Arp[((kb + 1) << 5) + 8];
      b8 = *(const s16x8*)&Brp[((kb + 1) << 5)];
    }
    __syncthreads();
    s16x8 afr[4], bfr[2];
#pragma unroll
    for (int im = 0; im < 4; ++im)
      afr[im] = *(const s16x8*)&Asm[(wm * 64 + im * 16 + l15) * 40 + (g4 << 3)];
#pragma unroll
    for (int in = 0; in < 2; ++in)
      bfr[in] = *(const s16x8*)&Bsm[(wn * 32 + in * 16 + l15) * 40 + (g4 << 3)];
#pragma unroll
    for (int im = 0; im < 4; ++im)
#pragma unroll
      for (int in = 0; in < 2; ++in)
        acc[im][in] = __builtin_amdgcn_mfma_f32_16x16x32_bf16(afr[im], bfr[in], acc[im][in], 0, 0, 0);
  }
  long grow0 = (long)b0 * 512 + (long)tile * 128 + wm * 64 + (g4 << 2);
#pragma unroll
  for (int in = 0; in < 2; ++in) {
    int colg = (h << 6) + wn * 32 + in * 16 + l15;
    float bvv = bv[colg];
#pragma unroll
    for (int im = 0; im < 4; ++im) {
      long rowg = grow0 + im * 16;
#pragma unroll
      for (int r = 0; r < 4; ++r)
        av[(rowg + r) * 1024 + colg] = f2bf(acc[im][in][r] + bvv);
    }
  }
}

// ---- K4: yb = bf16(AV @ wo + bo)  (128x128 tiles) ----
__global__ __launch_bounds__(256) void k_out(
    const unsigned short* __restrict__ av, const unsigned short* __restrict__ wot,
    const float* __restrict__ bo, unsigned short* __restrict__ yb) {
  __shared__ short Asm[128 * 40];
  __shared__ short Bsm[128 * 40];
  int mt = blockIdx.x, nt = blockIdx.y, t = threadIdx.x;
  int lane = t & 63, w = t >> 6;
  int wm = w >> 1, wn = w & 1;
  int l15 = lane & 15, g4 = lane >> 4;
  f32x4 acc[4][4] = {};
  int lr = t >> 1, ls = (t & 1) << 4;
  const unsigned short* Ar = av + ((long)(mt * 128 + lr)) * 1024;
  const unsigned short* Br = wot + ((long)(nt * 128 + lr)) * 1024;
  s16x8 a0 = *(const s16x8*)&Ar[ls];
  s16x8 a1 = *(const s16x8*)&Ar[ls + 8];
  s16x8 b0 = *(const s16x8*)&Br[ls];
  s16x8 b1 = *(const s16x8*)&Br[ls + 8];
  for (int kb = 0; kb < 32; ++kb) {
    __syncthreads();
    short* pa = &Asm[lr * 40 + ls];
    *(s16x8*)pa = a0; *(s16x8*)(pa + 8) = a1;
    short* pb = &Bsm[lr * 40 + ls];
    *(s16x8*)pb = b0; *(s16x8*)(pb + 8) = b1;
    if (kb + 1 < 32) {
      a0 = *(const s16x8*)&Ar[((kb + 1) << 5) + ls];
      a1 = *(const s16x8*)&Ar[((kb + 1) << 5) + ls + 8];
      b0 = *(const s16x8*)&Br[((kb + 1) << 5) + ls];
      b1 = *(const s16x8*)&Br[((kb + 1) << 5) + ls + 8];
    }
    __syncthreads();
    s16x8 afr[4], bfr[4];
#pragma unroll
    for (int im = 0; im < 4; ++im)
      afr[im] = *(const s16x8*)&Asm[(wm * 64 + im * 16 + l15) * 40 + (g4 << 3)];
#pragma unroll
    for (int in = 0; in < 4; ++in)
      bfr[in] = *(const s16x8*)&Bsm[(wn * 64 + in * 16 + l15) * 40 + (g4 << 3)];
#pragma unroll
    for (int im = 0; im < 4; ++im)
#pragma unroll
      for (int in = 0; in < 4; ++in)
        acc[im][in] = __builtin_amdgcn_mfma_f32_16x16x32_bf16(afr[im], bfr[in], acc[im][in], 0, 0, 0);
  }
#pragma unroll
  for (int in = 0; in < 4; ++in) {
    int colg = nt * 128 + wn * 64 + in * 16 + l15;
    float bov = bo[colg];
#pragma unroll
    for (int im = 0; im < 4; ++im) {
      long rowg = mt * 128 + wm * 64 + im * 16 + (g4 << 2);
#pragma unroll
      for (int r = 0; r < 4; ++r)
        yb[(rowg + r) * 1024 + colg] = f2bf(acc[im][in][r] + bov);
    }
  }
}

// ---- K5: y = LayerNorm(yb) over last dim (bf16 in, f32 out) ----
__global__ __launch_bounds__(256) void k_ln(
    const unsigned short* __restrict__ yb, const float* __restrict__ gamma,
    const float* __restrict__ beta, float* __restrict__ y) {
  int row = (blockIdx.x << 2) + (threadIdx.x >> 6);
  int lane = threadIdx.x & 63;
  const unsigned short* yr = yb + ((long)row << 10);
  float v[4][4];
  float s = 0.f, s2 = 0.f;
#pragma unroll
  for (int j = 0; j < 4; ++j) {
    s16x4 h4 = *(const s16x4*)&yr[(lane << 2) + (j << 8)];
#pragma unroll
    for (int q = 0; q < 4; ++q) {
      float f = bf2f((unsigned short)h4[q]);
      v[j][q] = f; s += f; s2 += f * f;
    }
  }
#pragma unroll
  for (int d = 1; d < 64; d <<= 1) {
    s += __shfl_xor(s, d, 64);
    s2 += __shfl_xor(s2, d, 64);
  }
  float mu = s * (1.0f / 1024.0f);
  float var = s2 * (1.0f / 1024.0f) - mu * mu;
  float rs = rsqrtf(var + 1e-5f);
  float* yo = y + ((long)row << 10);
#pragma unroll
  for (int j = 0; j < 4; ++j) {
    int f0 = (lane << 2) + (j << 8);
    f32x4 gm = *(const f32x4*)&gamma[f0];
    f32x4 bt = *(const f32x4*)&beta[f0];
    f32x4 o;
#pragma unroll
    for (int q = 0; q < 4; ++q) o[q] = (v[j][q] - mu) * rs * gm[q] + bt[q];
    *(f32x4*)&yo[f0] = o;
  }
}

extern "C" void kernel_launch(void* const* d_in, const int* in_sizes, int n_in,
                              void* d_out, int out_size, void* d_ws, size_t ws_size,
                              hipStream_t stream) {
  (void)in_sizes; (void)n_in; (void)out_size;
  const float* cq    = (const float*)d_in[0];
  const float* G     = (const float*)d_in[1];
  const float* conf  = (const float*)d_in[2];
  const float* wq    = (const float*)d_in[3];
  const float* bq    = (const float*)d_in[4];
  const float* wk    = (const float*)d_in[5];
  const float* bk    = (const float*)d_in[6];
  const float* wv    = (const float*)d_in[7];
  const float* bv    = (const float*)d_in[8];
  const float* wo    = (const float*)d_in[9];
  const float* bo    = (const float*)d_in[10];
  const float* gamma = (const float*)d_in[11];
  const float* beta  = (const float*)d_in[12];

  float* y = (float*)d_out;
  float* alpha = y + 4194304;  // out (8*512*1024) then alpha (8*512*16*16)

  char* p = (char*)d_ws;
  float* qpart = (float*)p;                  p += 8L * 16 * 1024 * 4;   // 512KB
  float* cvec  = (float*)p;                  p += 1024;
  unsigned short* wt   = (unsigned short*)p; p += 8L * 16 * 1024 * 2;   // 256KB
  unsigned short* wvt  = (unsigned short*)p; p += 1024L * 1024 * 2;     // 2MB
  unsigned short* wot  = (unsigned short*)p; p += 1024L * 1024 * 2;     // 2MB
  unsigned short* av   = (unsigned short*)p; p += 4096L * 1024 * 2;     // 8MB
  unsigned short* yb   = (unsigned short*)p; p += 4096L * 1024 * 2;     // 8MB
  unsigned short* gbar = (unsigned short*)p;
  size_t used = (size_t)(p - (char*)d_ws);
  size_t per_b = 512L * 16 * 1024 * 2;  // 16MB of Gbar per batch
  int nb = 1;
  if (ws_size >= used + 8 * per_b) nb = 8;
  else if (ws_size >= used + 4 * per_b) nb = 4;
  else if (ws_size >= used + 2 * per_b) nb = 2;
  int hstride = nb * 512 * 1024;  // u16 elements per h-plane of gbar

  hipLaunchKernelGGL(k_transq, dim3(576), dim3(256), 0, stream,
                     wv, wo, wvt, wot, cq, wq, qpart);
  hipLaunchKernelGGL(k_wtilde, dim3(8, 8), dim3(256), 0, stream, wk, bk, bq, qpart, wt, cvec);
  for (int c = 0; c < 8; c += nb) {
    hipLaunchKernelGGL(k_scores, dim3(nb * 512), dim3(256), 0, stream,
                       G, conf, wt, cvec, alpha, gbar, c, hstride);
    hipLaunchKernelGGL(k_av, dim3(nb * 4, 16), dim3(256), 0, stream,
                       gbar, wvt, bv, av, c, hstride);
  }
  hipLaunchKernelGGL(k_out, dim3(32, 8), dim3(256), 0, stream, av, wot, bo, yb);
  hipLaunchKernelGGL(k_ln, dim3(1024), dim3(256), 0, stream, yb, gamma, beta, y);
}

// Round 10
// 201.492 us; speedup vs baseline: 1.3858x; 1.0569x over previous
//
#include <hip/hip_runtime.h>

// FacetCrossAttention: B=8, P=512, K=16, H=16, D=1024, DH=64
// Factorized pipeline (bf16 MFMA, f32 accum):
//   Wt[b,e,h] = sum_dh wk[e,h*64+dh] Q[b,h*64+dh];  c[b,h] = bk . Q_h
//   scores[h,k] = (G[k,:].Wt[:,h] + c)/8 + log(conf)   (per b,p; MFMA)
//   alpha = sparsemax_k (shuffle bitonic sort + scan + ballot)
//   Gbar[h,:] = sum_k alpha[h,k] G[k,:]   (MFMA; A = G^T via write-side transpose)
//   AV = Gbar_h @ wv_h + bv  (per-h GEMM, 64x64 tiles, 4 blocks/CU)
//   yb = bf16(AV @ wo + bo)  (64x64 tiles, 4 blocks/CU); y = LayerNorm(yb).

typedef float f32x4 __attribute__((ext_vector_type(4)));
typedef short s16x4 __attribute__((ext_vector_type(4)));
typedef short s16x8 __attribute__((ext_vector_type(8)));

__device__ __forceinline__ unsigned short f2bf(float f) {
  unsigned u = __builtin_bit_cast(unsigned, f);
  u = (u + 0x7FFFu + ((u >> 16) & 1u)) >> 16;
  return (unsigned short)u;
}

__device__ __forceinline__ float bf2f(unsigned short u) {
  return __builtin_bit_cast(float, ((unsigned)u) << 16);
}

__device__ __forceinline__ s16x8 pack8(s16x4 lo, s16x4 hi) {
  s16x8 r;
  r[0] = lo[0]; r[1] = lo[1]; r[2] = lo[2]; r[3] = lo[3];
  r[4] = hi[0]; r[5] = hi[1]; r[6] = hi[2]; r[7] = hi[3];
  return r;
}

// ---- K0: fused {transpose wv/wo to bf16 [col][k]} + {qpart, 64-block} ----
__global__ __launch_bounds__(256) void k_transq(
    const float* __restrict__ wv, const float* __restrict__ wo,
    unsigned short* __restrict__ wvt, unsigned short* __restrict__ wot,
    const float* __restrict__ cq, const float* __restrict__ wq,
    float* __restrict__ qpart) {
  int bid = blockIdx.x;
  int t = threadIdx.x;
  if (bid < 512) {
    __shared__ float ts[64][65];
    const float* src = (bid < 256) ? wv : wo;
    unsigned short* dst = (bid < 256) ? wvt : wot;
    int tile = bid & 255;
    int er = (tile >> 4) << 6;
    int cb = (tile & 15) << 6;
    int r = t >> 2, c0 = (t & 3) << 4;
#pragma unroll
    for (int j = 0; j < 16; j += 4) {
      f32x4 v = *(const f32x4*)&src[(long)(er + r) * 1024 + cb + c0 + j];
      ts[r][c0 + j + 0] = v[0];
      ts[r][c0 + j + 1] = v[1];
      ts[r][c0 + j + 2] = v[2];
      ts[r][c0 + j + 3] = v[3];
    }
    __syncthreads();
    s16x8 o0, o1;
#pragma unroll
    for (int j = 0; j < 8; ++j) o0[j] = (short)f2bf(ts[c0 + j][r]);
#pragma unroll
    for (int j = 0; j < 8; ++j) o1[j] = (short)f2bf(ts[c0 + 8 + j][r]);
    long ob = (long)(cb + r) * 1024 + er + c0;
    *(s16x8*)&dst[ob] = o0;
    *(s16x8*)&dst[ob + 8] = o1;
  } else {
    // qpart[b][eq][d] = sum_{e in eq-chunk} cq[b,e] wq[e,d]
    int idx = bid - 512;
    int eq = idx >> 2, dq = idx & 3;
    int d = (dq << 8) + t;
    float acc[8] = {};
    for (int i = 0; i < 64; ++i) {
      int e = (eq << 6) + i;
      float w = wq[(long)e * 1024 + d];
#pragma unroll
      for (int b = 0; b < 8; ++b) acc[b] += w * cq[(b << 10) + e];
    }
#pragma unroll
    for (int b = 0; b < 8; ++b)
      qpart[(long)((b << 4) + eq) * 1024 + d] = acc[b];
  }
}

// ---- K1: Wt[b][h][e] (bf16) and c[b][h]; 256 blocks (1/CU) ----
__global__ __launch_bounds__(256) void k_wtilde(
    const float* __restrict__ wk, const float* __restrict__ bk,
    const float* __restrict__ bq, const float* __restrict__ qpart,
    unsigned short* __restrict__ wt, float* __restrict__ cvec) {
  __shared__ float Qs[16][68];
  int et = blockIdx.x, b = blockIdx.y, t = threadIdx.x;
  {
    int d0 = t << 2;
    f32x4 s4 = *(const f32x4*)&bq[d0];
#pragma unroll
    for (int q = 0; q < 16; ++q)
      s4 += *(const f32x4*)&qpart[(long)((b << 4) + q) * 1024 + d0];
    *(f32x4*)&Qs[d0 >> 6][d0 & 63] = s4;
  }
  __syncthreads();
  int h = t & 15, el = t >> 4;
#pragma unroll
  for (int ii = 0; ii < 2; ++ii) {
    int e = (et << 5) + (ii << 4) + el;
    const float* wr = &wk[(long)e * 1024 + (h << 6)];
    float s = 0.f;
#pragma unroll
    for (int d = 0; d < 64; d += 4) {
      f32x4 w = *(const f32x4*)&wr[d];
      s += w[0] * Qs[h][d] + w[1] * Qs[h][d + 1] + w[2] * Qs[h][d + 2] + w[3] * Qs[h][d + 3];
    }
    wt[(long)((b << 4) + h) * 1024 + e] = f2bf(s);
  }
  if (et == 0 && t < 16) {
    float s = 0.f;
    for (int d = 0; d < 64; ++d) s += bk[(t << 6) + d] * Qs[t][d];
    cvec[(b << 4) + t] = s;
  }
}

// ---- K2: per (b,p): scores -> sparsemax -> Gbar (h-major global) ----
#define GSTR 1028
#define TSTR 20
__global__ __launch_bounds__(256, 2) void k_scores(
    const float* __restrict__ G, const float* __restrict__ conf,
    const unsigned short* __restrict__ wt, const float* __restrict__ cvec,
    float* __restrict__ alpha_out, unsigned short* __restrict__ gbar,
    int b0, int hstride) {
  __shared__ short Gs[16 * GSTR];    // [k][e] row-major (phase 1 B-operand)
  __shared__ short Gt[1024 * TSTR];  // [e][kf] transposed (phase 2 A-operand)
  __shared__ short As[16 * 32];      // alpha bf16, zero-padded kf in [16,32)
  __shared__ float ps[1024];
  __shared__ float lc[16];

  int t = threadIdx.x;
  int lane = t & 63, w = t >> 6;
  int l15 = lane & 15, g4 = lane >> 4;
  int bp = blockIdx.x;
  long gbp = (long)b0 * 512 + bp;
  int b = (int)(gbp >> 9);
  const float* Grow = G + gbp * 16384;
  const unsigned short* wtb = wt + (long)b * 16384;

  // load G: thread t owns e = 4t..4t+3; write Gs [k][e] and Gt [e][kf]
#pragma unroll
  for (int half = 0; half < 2; ++half) {
    s16x4 col[8];
#pragma unroll
    for (int j = 0; j < 8; ++j) {
      int k = (half << 3) + j;
      f32x4 g = *(const f32x4*)&Grow[(k << 10) + (t << 2)];
      s16x4 h4;
      h4[0] = (short)f2bf(g[0]); h4[1] = (short)f2bf(g[1]);
      h4[2] = (short)f2bf(g[2]); h4[3] = (short)f2bf(g[3]);
      *(s16x4*)&Gs[k * GSTR + (t << 2)] = h4;
      col[j] = h4;
    }
#pragma unroll
    for (int q = 0; q < 4; ++q) {
      int e = (t << 2) + q;
      s16x4 lo, hi;
      lo[0] = col[0][q]; lo[1] = col[1][q]; lo[2] = col[2][q]; lo[3] = col[3][q];
      hi[0] = col[4][q]; hi[1] = col[5][q]; hi[2] = col[6][q]; hi[3] = col[7][q];
      *(s16x4*)&Gt[e * TSTR + (half << 3)] = lo;
      *(s16x4*)&Gt[e * TSTR + (half << 3) + 4] = hi;
    }
  }
  if (t < 16) lc[t] = logf(fmaxf(conf[gbp * 16 + t], 1e-6f));
  __syncthreads();

  // phase 1: scores^T[h][kf] partials; A = Wt rows (direct global), B = Gs rows
  f32x4 sc = {0.f, 0.f, 0.f, 0.f};
#pragma unroll
  for (int i = 0; i < 8; ++i) {
    int e0 = (w << 8) + (i << 5) + (g4 << 3);
    s16x8 af = *(const s16x8*)&wtb[l15 * 1024 + e0];
    int off = l15 * GSTR + e0;
    s16x8 bf = pack8(*(const s16x4*)&Gs[off], *(const s16x4*)&Gs[off + 4]);
    sc = __builtin_amdgcn_mfma_f32_16x16x32_bf16(af, bf, sc, 0, 0, 0);
  }
#pragma unroll
  for (int r = 0; r < 4; ++r)
    ps[(w << 8) + ((g4 << 2) + r) * 16 + l15] = sc[r];
  __syncthreads();

  // sparsemax: thread (h = t>>4, k = t&15); 16-lane groups via shuffles
  {
    int h = t >> 4, k = t & 15;
    float z = (ps[h * 16 + k] + ps[256 + h * 16 + k] + ps[512 + h * 16 + k] +
               ps[768 + h * 16 + k] + cvec[b * 16 + h]) * 0.125f + lc[k];
    float v = z;
#pragma unroll
    for (int kk = 2; kk <= 16; kk <<= 1) {
#pragma unroll
      for (int j = kk >> 1; j > 0; j >>= 1) {
        float o = __shfl_xor(v, j, 64);
        bool dirDesc = ((l15 & kk) == 0);
        bool takeMax = (((l15 & j) == 0) == dirDesc);
        v = takeMax ? fmaxf(v, o) : fminf(v, o);
      }
    }
    float cs = v;
#pragma unroll
    for (int d = 1; d < 16; d <<= 1) {
      float o = __shfl_up(cs, (unsigned)d, 16);
      if (l15 >= d) cs += o;
    }
    bool sup = (1.0f + (float)(l15 + 1) * v) > cs;
    unsigned long long m = __ballot(sup);
    int gb16 = lane & 48;
    int ksup = (int)__popcll((m >> gb16) & 0xFFFFull);
    float csk = __shfl(cs, ksup - 1, 16);
    float tau = (csk - 1.0f) / (float)ksup;
    float a = fmaxf(z - tau, 0.0f);
    alpha_out[((gbp << 4) + h) * 16 + k] = a;
    As[(h << 5) + k] = (short)f2bf(a);
    As[(h << 5) + 16 + k] = 0;
  }
  __syncthreads();

  // phase 2: Gbar^T: A = Gt rows (e-major, kf contiguous), B = alpha.
  // g4>=2 lanes re-read kf 0..15 (finite); annihilated by exact-zero alpha pad.
  s16x8 ab = *(const s16x8*)&As[(l15 << 5) + (g4 << 3)];
#pragma unroll 4
  for (int i = 0; i < 16; ++i) {
    int ebase = ((w << 4) + i) << 4;
    int ro = (ebase + l15) * TSTR + ((g4 & 1) << 3);
    s16x8 aa = pack8(*(const s16x4*)&Gt[ro], *(const s16x4*)&Gt[ro + 4]);
    f32x4 d2 = __builtin_amdgcn_mfma_f32_16x16x32_bf16(
        aa, ab, (f32x4){0.f, 0.f, 0.f, 0.f}, 0, 0, 0);
    s16x4 o4;
    o4[0] = (short)f2bf(d2[0]); o4[1] = (short)f2bf(d2[1]);
    o4[2] = (short)f2bf(d2[2]); o4[3] = (short)f2bf(d2[3]);
    // D: col = h = l15, rows = e = ebase + g4*4 + r; store into [h][bp][e]
    *(s16x4*)&gbar[(long)l15 * hstride + (long)bp * 1024 + ebase + (g4 << 2)] = o4;
  }
}

// ---- K3: AV[bp, h*64+c] = Gbar_h[bp,:] @ wvt[h*64+c,:] + bv ----
// 64x64 tile, grid (nb*8, 16) = 1024 blocks at nb=8 -> 4 blocks/CU.
__global__ __launch_bounds__(256) void k_av(
    const unsigned short* __restrict__ gbar, const unsigned short* __restrict__ wvt,
    const float* __restrict__ bv, unsigned short* __restrict__ av,
    int b0, int hstride) {
  __shared__ short Asm[64 * 40];
  __shared__ short Bsm[64 * 40];
  int t = threadIdx.x;
  int lane = t & 63, w = t >> 6;
  int l15 = lane & 15, g4 = lane >> 4;
  int wm = w >> 1, wn = w & 1;
  int tile = blockIdx.x, h = blockIdx.y;
  const unsigned short* Ab = gbar + (long)h * hstride + (long)tile * 64 * 1024;
  const unsigned short* Bb = wvt + (long)(h << 6) * 1024;
  int lr = t >> 2, lc = (t & 3) << 3;
  const unsigned short* Arp = Ab + (long)lr * 1024 + lc;
  const unsigned short* Brp = Bb + (long)lr * 1024 + lc;
  s16x8 a8 = *(const s16x8*)&Arp[0];
  s16x8 b8 = *(const s16x8*)&Brp[0];
  f32x4 acc[2][2] = {};
  for (int kb = 0; kb < 32; ++kb) {
    __syncthreads();
    *(s16x8*)&Asm[lr * 40 + lc] = a8;
    *(s16x8*)&Bsm[lr * 40 + lc] = b8;
    if (kb + 1 < 32) {
      a8 = *(const s16x8*)&Arp[((kb + 1) << 5)];
      b8 = *(const s16x8*)&Brp[((kb + 1) << 5)];
    }
    __syncthreads();
    s16x8 afr[2], bfr[2];
#pragma unroll
    for (int im = 0; im < 2; ++im)
      afr[im] = *(const s16x8*)&Asm[(wm * 32 + im * 16 + l15) * 40 + (g4 << 3)];
#pragma unroll
    for (int in = 0; in < 2; ++in)
      bfr[in] = *(const s16x8*)&Bsm[(wn * 32 + in * 16 + l15) * 40 + (g4 << 3)];
#pragma unroll
    for (int im = 0; im < 2; ++im)
#pragma unroll
      for (int in = 0; in < 2; ++in)
        acc[im][in] = __builtin_amdgcn_mfma_f32_16x16x32_bf16(afr[im], bfr[in], acc[im][in], 0, 0, 0);
  }
  long grow0 = (long)b0 * 512 + (long)tile * 64 + wm * 32 + (g4 << 2);
#pragma unroll
  for (int in = 0; in < 2; ++in) {
    int colg = (h << 6) + wn * 32 + in * 16 + l15;
    float bvv = bv[colg];
#pragma unroll
    for (int im = 0; im < 2; ++im) {
      long rowg = grow0 + im * 16;
#pragma unroll
      for (int r = 0; r < 4; ++r)
        av[(rowg + r) * 1024 + colg] = f2bf(acc[im][in][r] + bvv);
    }
  }
}

// ---- K4: yb = bf16(AV @ wo + bo)  64x64 tiles, grid (64,16) -> 4 blocks/CU ----
__global__ __launch_bounds__(256) void k_out(
    const unsigned short* __restrict__ av, const unsigned short* __restrict__ wot,
    const float* __restrict__ bo, unsigned short* __restrict__ yb) {
  __shared__ short Asm[64 * 40];
  __shared__ short Bsm[64 * 40];
  int mt = blockIdx.x, nt = blockIdx.y, t = threadIdx.x;
  int lane = t & 63, w = t >> 6;
  int wm = w >> 1, wn = w & 1;
  int l15 = lane & 15, g4 = lane >> 4;
  int lr = t >> 2, lc = (t & 3) << 3;
  const unsigned short* Arp = av + (long)(mt * 64 + lr) * 1024 + lc;
  const unsigned short* Brp = wot + (long)(nt * 64 + lr) * 1024 + lc;
  s16x8 a8 = *(const s16x8*)&Arp[0];
  s16x8 b8 = *(const s16x8*)&Brp[0];
  f32x4 acc[2][2] = {};
  for (int kb = 0; kb < 32; ++kb) {
    __syncthreads();
    *(s16x8*)&Asm[lr * 40 + lc] = a8;
    *(s16x8*)&Bsm[lr * 40 + lc] = b8;
    if (kb + 1 < 32) {
      a8 = *(const s16x8*)&Arp[((kb + 1) << 5)];
      b8 = *(const s16x8*)&Brp[((kb + 1) << 5)];
    }
    __syncthreads();
    s16x8 afr[2], bfr[2];
#pragma unroll
    for (int im = 0; im < 2; ++im)
      afr[im] = *(const s16x8*)&Asm[(wm * 32 + im * 16 + l15) * 40 + (g4 << 3)];
#pragma unroll
    for (int in = 0; in < 2; ++in)
      bfr[in] = *(const s16x8*)&Bsm[(wn * 32 + in * 16 + l15) * 40 + (g4 << 3)];
#pragma unroll
    for (int im = 0; im < 2; ++im)
#pragma unroll
      for (int in = 0; in < 2; ++in)
        acc[im][in] = __builtin_amdgcn_mfma_f32_16x16x32_bf16(afr[im], bfr[in], acc[im][in], 0, 0, 0);
  }
#pragma unroll
  for (int in = 0; in < 2; ++in) {
    int colg = nt * 64 + wn * 32 + in * 16 + l15;
    float bov = bo[colg];
#pragma unroll
    for (int im = 0; im < 2; ++im) {
      long rowg = (long)mt * 64 + wm * 32 + im * 16 + (g4 << 2);
#pragma unroll
      for (int r = 0; r < 4; ++r)
        yb[(rowg + r) * 1024 + colg] = f2bf(acc[im][in][r] + bov);
    }
  }
}

// ---- K5: y = LayerNorm(yb) over last dim (bf16 in, f32 out) ----
__global__ __launch_bounds__(256) void k_ln(
    const unsigned short* __restrict__ yb, const float* __restrict__ gamma,
    const float* __restrict__ beta, float* __restrict__ y) {
  int row = (blockIdx.x << 2) + (threadIdx.x >> 6);
  int lane = threadIdx.x & 63;
  const unsigned short* yr = yb + ((long)row << 10);
  float v[4][4];
  float s = 0.f, s2 = 0.f;
#pragma unroll
  for (int j = 0; j < 4; ++j) {
    s16x4 h4 = *(const s16x4*)&yr[(lane << 2) + (j << 8)];
#pragma unroll
    for (int q = 0; q < 4; ++q) {
      float f = bf2f((unsigned short)h4[q]);
      v[j][q] = f; s += f; s2 += f * f;
    }
  }
#pragma unroll
  for (int d = 1; d < 64; d <<= 1) {
    s += __shfl_xor(s, d, 64);
    s2 += __shfl_xor(s2, d, 64);
  }
  float mu = s * (1.0f / 1024.0f);
  float var = s2 * (1.0f / 1024.0f) - mu * mu;
  float rs = rsqrtf(var + 1e-5f);
  float* yo = y + ((long)row << 10);
#pragma unroll
  for (int j = 0; j < 4; ++j) {
    int f0 = (lane << 2) + (j << 8);
    f32x4 gm = *(const f32x4*)&gamma[f0];
    f32x4 bt = *(const f32x4*)&beta[f0];
    f32x4 o;
#pragma unroll
    for (int q = 0; q < 4; ++q) o[q] = (v[j][q] - mu) * rs * gm[q] + bt[q];
    *(f32x4*)&yo[f0] = o;
  }
}

extern "C" void kernel_launch(void* const* d_in, const int* in_sizes, int n_in,
                              void* d_out, int out_size, void* d_ws, size_t ws_size,
                              hipStream_t stream) {
  (void)in_sizes; (void)n_in; (void)out_size;
  const float* cq    = (const float*)d_in[0];
  const float* G     = (const float*)d_in[1];
  const float* conf  = (const float*)d_in[2];
  const float* wq    = (const float*)d_in[3];
  const float* bq    = (const float*)d_in[4];
  const float* wk    = (const float*)d_in[5];
  const float* bk    = (const float*)d_in[6];
  const float* wv    = (const float*)d_in[7];
  const float* bv    = (const float*)d_in[8];
  const float* wo    = (const float*)d_in[9];
  const float* bo    = (const float*)d_in[10];
  const float* gamma = (const float*)d_in[11];
  const float* beta  = (const float*)d_in[12];

  float* y = (float*)d_out;
  float* alpha = y + 4194304;  // out (8*512*1024) then alpha (8*512*16*16)

  char* p = (char*)d_ws;
  float* qpart = (float*)p;                  p += 8L * 16 * 1024 * 4;   // 512KB
  float* cvec  = (float*)p;                  p += 1024;
  unsigned short* wt   = (unsigned short*)p; p += 8L * 16 * 1024 * 2;   // 256KB
  unsigned short* wvt  = (unsigned short*)p; p += 1024L * 1024 * 2;     // 2MB
  unsigned short* wot  = (unsigned short*)p; p += 1024L * 1024 * 2;     // 2MB
  unsigned short* av   = (unsigned short*)p; p += 4096L * 1024 * 2;     // 8MB
  unsigned short* yb   = (unsigned short*)p; p += 4096L * 1024 * 2;     // 8MB
  unsigned short* gbar = (unsigned short*)p;
  size_t used = (size_t)(p - (char*)d_ws);
  size_t per_b = 512L * 16 * 1024 * 2;  // 16MB of Gbar per batch
  int nb = 1;
  if (ws_size >= used + 8 * per_b) nb = 8;
  else if (ws_size >= used + 4 * per_b) nb = 4;
  else if (ws_size >= used + 2 * per_b) nb = 2;
  int hstride = nb * 512 * 1024;  // u16 elements per h-plane of gbar

  hipLaunchKernelGGL(k_transq, dim3(576), dim3(256), 0, stream,
                     wv, wo, wvt, wot, cq, wq, qpart);
  hipLaunchKernelGGL(k_wtilde, dim3(32, 8), dim3(256), 0, stream, wk, bk, bq, qpart, wt, cvec);
  for (int c = 0; c < 8; c += nb) {
    hipLaunchKernelGGL(k_scores, dim3(nb * 512), dim3(256), 0, stream,
                       G, conf, wt, cvec, alpha, gbar, c, hstride);
    hipLaunchKernelGGL(k_av, dim3(nb * 8, 16), dim3(256), 0, stream,
                       gbar, wvt, bv, av, c, hstride);
  }
  hipLaunchKernelGGL(k_out, dim3(64, 16), dim3(256), 0, stream, av, wot, bo, yb);
  hipLaunchKernelGGL(k_ln, dim3(1024), dim3(256), 0, stream, yb, gamma, beta, y);
}

// Round 11
// 188.338 us; speedup vs baseline: 1.4826x; 1.0698x over previous
//
#include <hip/hip_runtime.h>

// FacetCrossAttention: B=8, P=512, K=16, H=16, D=1024, DH=64
// Factorized pipeline (bf16 MFMA, f32 accum):
//   Wt[b,e,h] = sum_dh wk[e,h*64+dh] Q[b,h*64+dh];  c[b,h] = bk . Q_h
//   scores[h,k] = (G[k,:].Wt[:,h] + c)/8 + log(conf)   (per b,p; MFMA)
//   alpha = sparsemax_k (shuffle bitonic sort + scan + ballot)
//   Gbar[h,:] = sum_k alpha[h,k] G[k,:]  (MFMA; coalesced store via LDS re-stage)
//   AV = Gbar_h @ wv_h + bv  (per-h GEMM, 32x64 tiles, nb=4 chunks for L3 reuse)
//   yb = bf16(AV @ wo + bo)  (64x64 tiles); y = LayerNorm(yb).

typedef float f32x4 __attribute__((ext_vector_type(4)));
typedef short s16x4 __attribute__((ext_vector_type(4)));
typedef short s16x8 __attribute__((ext_vector_type(8)));

__device__ __forceinline__ unsigned short f2bf(float f) {
  unsigned u = __builtin_bit_cast(unsigned, f);
  u = (u + 0x7FFFu + ((u >> 16) & 1u)) >> 16;
  return (unsigned short)u;
}

__device__ __forceinline__ float bf2f(unsigned short u) {
  return __builtin_bit_cast(float, ((unsigned)u) << 16);
}

__device__ __forceinline__ s16x8 pack8(s16x4 lo, s16x4 hi) {
  s16x8 r;
  r[0] = lo[0]; r[1] = lo[1]; r[2] = lo[2]; r[3] = lo[3];
  r[4] = hi[0]; r[5] = hi[1]; r[6] = hi[2]; r[7] = hi[3];
  return r;
}

// ---- K0: fused {transpose wv/wo to bf16 [col][k]} + {qpart, 64-block} ----
__global__ __launch_bounds__(256) void k_transq(
    const float* __restrict__ wv, const float* __restrict__ wo,
    unsigned short* __restrict__ wvt, unsigned short* __restrict__ wot,
    const float* __restrict__ cq, const float* __restrict__ wq,
    float* __restrict__ qpart) {
  int bid = blockIdx.x;
  int t = threadIdx.x;
  if (bid < 512) {
    __shared__ float ts[64][65];
    const float* src = (bid < 256) ? wv : wo;
    unsigned short* dst = (bid < 256) ? wvt : wot;
    int tile = bid & 255;
    int er = (tile >> 4) << 6;
    int cb = (tile & 15) << 6;
    int r = t >> 2, c0 = (t & 3) << 4;
#pragma unroll
    for (int j = 0; j < 16; j += 4) {
      f32x4 v = *(const f32x4*)&src[(long)(er + r) * 1024 + cb + c0 + j];
      ts[r][c0 + j + 0] = v[0];
      ts[r][c0 + j + 1] = v[1];
      ts[r][c0 + j + 2] = v[2];
      ts[r][c0 + j + 3] = v[3];
    }
    __syncthreads();
    s16x8 o0, o1;
#pragma unroll
    for (int j = 0; j < 8; ++j) o0[j] = (short)f2bf(ts[c0 + j][r]);
#pragma unroll
    for (int j = 0; j < 8; ++j) o1[j] = (short)f2bf(ts[c0 + 8 + j][r]);
    long ob = (long)(cb + r) * 1024 + er + c0;
    *(s16x8*)&dst[ob] = o0;
    *(s16x8*)&dst[ob + 8] = o1;
  } else {
    // qpart[b][eq][d] = sum_{e in eq-chunk} cq[b,e] wq[e,d]
    int idx = bid - 512;
    int eq = idx >> 2, dq = idx & 3;
    int d = (dq << 8) + t;
    float acc[8] = {};
    for (int i = 0; i < 64; ++i) {
      int e = (eq << 6) + i;
      float w = wq[(long)e * 1024 + d];
#pragma unroll
      for (int b = 0; b < 8; ++b) acc[b] += w * cq[(b << 10) + e];
    }
#pragma unroll
    for (int b = 0; b < 8; ++b)
      qpart[(long)((b << 4) + eq) * 1024 + d] = acc[b];
  }
}

// ---- K1: Wt[b][h][e] (bf16) and c[b][h]; 256 blocks ----
__global__ __launch_bounds__(256) void k_wtilde(
    const float* __restrict__ wk, const float* __restrict__ bk,
    const float* __restrict__ bq, const float* __restrict__ qpart,
    unsigned short* __restrict__ wt, float* __restrict__ cvec) {
  __shared__ float Qs[16][68];
  int et = blockIdx.x, b = blockIdx.y, t = threadIdx.x;
  {
    int d0 = t << 2;
    f32x4 s4 = *(const f32x4*)&bq[d0];
#pragma unroll
    for (int q = 0; q < 16; ++q)
      s4 += *(const f32x4*)&qpart[(long)((b << 4) + q) * 1024 + d0];
    *(f32x4*)&Qs[d0 >> 6][d0 & 63] = s4;
  }
  __syncthreads();
  int h = t & 15, el = t >> 4;
#pragma unroll
  for (int ii = 0; ii < 2; ++ii) {
    int e = (et << 5) + (ii << 4) + el;
    const float* wr = &wk[(long)e * 1024 + (h << 6)];
    float s = 0.f;
#pragma unroll
    for (int d = 0; d < 64; d += 4) {
      f32x4 w = *(const f32x4*)&wr[d];
      s += w[0] * Qs[h][d] + w[1] * Qs[h][d + 1] + w[2] * Qs[h][d + 2] + w[3] * Qs[h][d + 3];
    }
    wt[(long)((b << 4) + h) * 1024 + e] = f2bf(s);
  }
  if (et == 0 && t < 16) {
    float s = 0.f;
    for (int d = 0; d < 64; ++d) s += bk[(t << 6) + d] * Qs[t][d];
    cvec[(b << 4) + t] = s;
  }
}

// ---- K2: per (b,p): scores -> sparsemax -> Gbar (coalesced h-major store) ----
#define GSTR 1028
#define TSTR 20
__global__ __launch_bounds__(256, 2) void k_scores(
    const float* __restrict__ G, const float* __restrict__ conf,
    const unsigned short* __restrict__ wt, const float* __restrict__ cvec,
    float* __restrict__ alpha_out, unsigned short* __restrict__ gbar,
    int b0, int hstride) {
  __shared__ short Gs[16 * GSTR];    // [k][e] (phase 1 B); reused as Tr[h][e] in phase 2
  __shared__ short Gt[1024 * TSTR];  // [e][kf] transposed (phase 2 A-operand)
  __shared__ short As[16 * 32];      // alpha bf16, zero-padded kf in [16,32)
  __shared__ float ps[1024];
  __shared__ float lc[16];

  int t = threadIdx.x;
  int lane = t & 63, w = t >> 6;
  int l15 = lane & 15, g4 = lane >> 4;
  int bp = blockIdx.x;
  long gbp = (long)b0 * 512 + bp;
  int b = (int)(gbp >> 9);
  const float* Grow = G + gbp * 16384;
  const unsigned short* wtb = wt + (long)b * 16384;

  // load G: thread t owns e = 4t..4t+3; write Gs [k][e] and Gt [e][kf]
#pragma unroll
  for (int half = 0; half < 2; ++half) {
    s16x4 col[8];
#pragma unroll
    for (int j = 0; j < 8; ++j) {
      int k = (half << 3) + j;
      f32x4 g = *(const f32x4*)&Grow[(k << 10) + (t << 2)];
      s16x4 h4;
      h4[0] = (short)f2bf(g[0]); h4[1] = (short)f2bf(g[1]);
      h4[2] = (short)f2bf(g[2]); h4[3] = (short)f2bf(g[3]);
      *(s16x4*)&Gs[k * GSTR + (t << 2)] = h4;
      col[j] = h4;
    }
#pragma unroll
    for (int q = 0; q < 4; ++q) {
      int e = (t << 2) + q;
      s16x4 lo, hi;
      lo[0] = col[0][q]; lo[1] = col[1][q]; lo[2] = col[2][q]; lo[3] = col[3][q];
      hi[0] = col[4][q]; hi[1] = col[5][q]; hi[2] = col[6][q]; hi[3] = col[7][q];
      *(s16x4*)&Gt[e * TSTR + (half << 3)] = lo;
      *(s16x4*)&Gt[e * TSTR + (half << 3) + 4] = hi;
    }
  }
  if (t < 16) lc[t] = logf(fmaxf(conf[gbp * 16 + t], 1e-6f));
  __syncthreads();

  // phase 1: scores^T[h][kf] partials; A = Wt rows (direct global), B = Gs rows
  f32x4 sc = {0.f, 0.f, 0.f, 0.f};
#pragma unroll
  for (int i = 0; i < 8; ++i) {
    int e0 = (w << 8) + (i << 5) + (g4 << 3);
    s16x8 af = *(const s16x8*)&wtb[l15 * 1024 + e0];
    int off = l15 * GSTR + e0;
    s16x8 bf = pack8(*(const s16x4*)&Gs[off], *(const s16x4*)&Gs[off + 4]);
    sc = __builtin_amdgcn_mfma_f32_16x16x32_bf16(af, bf, sc, 0, 0, 0);
  }
#pragma unroll
  for (int r = 0; r < 4; ++r)
    ps[(w << 8) + ((g4 << 2) + r) * 16 + l15] = sc[r];
  __syncthreads();

  // sparsemax: thread (h = t>>4, k = t&15); 16-lane groups via shuffles
  {
    int h = t >> 4, k = t & 15;
    float z = (ps[h * 16 + k] + ps[256 + h * 16 + k] + ps[512 + h * 16 + k] +
               ps[768 + h * 16 + k] + cvec[b * 16 + h]) * 0.125f + lc[k];
    float v = z;
#pragma unroll
    for (int kk = 2; kk <= 16; kk <<= 1) {
#pragma unroll
      for (int j = kk >> 1; j > 0; j >>= 1) {
        float o = __shfl_xor(v, j, 64);
        bool dirDesc = ((l15 & kk) == 0);
        bool takeMax = (((l15 & j) == 0) == dirDesc);
        v = takeMax ? fmaxf(v, o) : fminf(v, o);
      }
    }
    float cs = v;
#pragma unroll
    for (int d = 1; d < 16; d <<= 1) {
      float o = __shfl_up(cs, (unsigned)d, 16);
      if (l15 >= d) cs += o;
    }
    bool sup = (1.0f + (float)(l15 + 1) * v) > cs;
    unsigned long long m = __ballot(sup);
    int gb16 = lane & 48;
    int ksup = (int)__popcll((m >> gb16) & 0xFFFFull);
    float csk = __shfl(cs, ksup - 1, 16);
    float tau = (csk - 1.0f) / (float)ksup;
    float a = fmaxf(z - tau, 0.0f);
    alpha_out[((gbp << 4) + h) * 16 + k] = a;
    As[(h << 5) + k] = (short)f2bf(a);
    As[(h << 5) + 16 + k] = 0;
  }
  __syncthreads();

  // phase 2: Gbar^T: A = Gt rows (e-major, kf contiguous), B = alpha.
  // g4>=2 lanes re-read kf 0..15 (finite); annihilated by exact-zero alpha pad.
  // D (col=h, rows=e) staged into the dead Gs region as Tr[h][e] for coalescing.
  s16x8 ab = *(const s16x8*)&As[(l15 << 5) + (g4 << 3)];
#pragma unroll 4
  for (int i = 0; i < 16; ++i) {
    int ebase = ((w << 4) + i) << 4;
    int ro = (ebase + l15) * TSTR + ((g4 & 1) << 3);
    s16x8 aa = pack8(*(const s16x4*)&Gt[ro], *(const s16x4*)&Gt[ro + 4]);
    f32x4 d2 = __builtin_amdgcn_mfma_f32_16x16x32_bf16(
        aa, ab, (f32x4){0.f, 0.f, 0.f, 0.f}, 0, 0, 0);
    s16x4 o4;
    o4[0] = (short)f2bf(d2[0]); o4[1] = (short)f2bf(d2[1]);
    o4[2] = (short)f2bf(d2[2]); o4[3] = (short)f2bf(d2[3]);
    *(s16x4*)&Gs[l15 * GSTR + ebase + (g4 << 2)] = o4;  // Tr[h=l15][e]
  }
  __syncthreads();

  // coalesced gbar store: 16B/lane contiguous runs into [h][bp][e]
  unsigned short* gbo = gbar + (long)bp * 1024;
#pragma unroll
  for (int c2 = 0; c2 < 8; ++c2) {
    int flat = (c2 << 11) + (t << 3);
    int hh = flat >> 10, e = flat & 1023;
    s16x4 lo = *(const s16x4*)&Gs[hh * GSTR + e];
    s16x4 hi = *(const s16x4*)&Gs[hh * GSTR + e + 4];
    *(s16x8*)&gbo[(long)hh * hstride + e] = pack8(lo, hi);
  }
}

// ---- K3: AV[bp, h*64+c] = Gbar_h[bp,:] @ wvt[h*64+c,:] + bv ----
// 32x64 tile, grid (nb*16, 16): 1024 blocks at nb=4 -> 4 blocks/CU.
__global__ __launch_bounds__(256) void k_av(
    const unsigned short* __restrict__ gbar, const unsigned short* __restrict__ wvt,
    const float* __restrict__ bv, unsigned short* __restrict__ av,
    int b0, int hstride) {
  __shared__ short Asm[32 * 40];
  __shared__ short Bsm[64 * 40];
  int t = threadIdx.x;
  int lane = t & 63, w = t >> 6;
  int l15 = lane & 15, g4 = lane >> 4;
  int wm = w >> 1, wn = w & 1;
  int tile = blockIdx.x, h = blockIdx.y;
  const unsigned short* Ab = gbar + (long)h * hstride + (long)tile * 32 * 1024;
  const unsigned short* Bb = wvt + (long)(h << 6) * 1024;
  int ar = t >> 3, ac = (t & 7) << 2;
  int br = t >> 2, bc = (t & 3) << 3;
  const unsigned short* Arp = Ab + (long)ar * 1024 + ac;
  const unsigned short* Brp = Bb + (long)br * 1024 + bc;
  s16x4 a4 = *(const s16x4*)&Arp[0];
  s16x8 b8 = *(const s16x8*)&Brp[0];
  f32x4 acc[2] = {};
  for (int kb = 0; kb < 32; ++kb) {
    __syncthreads();
    *(s16x4*)&Asm[ar * 40 + ac] = a4;
    *(s16x8*)&Bsm[br * 40 + bc] = b8;
    if (kb + 1 < 32) {
      a4 = *(const s16x4*)&Arp[((kb + 1) << 5)];
      b8 = *(const s16x8*)&Brp[((kb + 1) << 5)];
    }
    __syncthreads();
    s16x8 afr = *(const s16x8*)&Asm[(wm * 16 + l15) * 40 + (g4 << 3)];
    s16x8 bfr[2];
#pragma unroll
    for (int in = 0; in < 2; ++in)
      bfr[in] = *(const s16x8*)&Bsm[(wn * 32 + in * 16 + l15) * 40 + (g4 << 3)];
#pragma unroll
    for (int in = 0; in < 2; ++in)
      acc[in] = __builtin_amdgcn_mfma_f32_16x16x32_bf16(afr, bfr[in], acc[in], 0, 0, 0);
  }
  long grow0 = (long)b0 * 512 + (long)tile * 32 + wm * 16 + (g4 << 2);
#pragma unroll
  for (int in = 0; in < 2; ++in) {
    int colg = (h << 6) + wn * 32 + in * 16 + l15;
    float bvv = bv[colg];
#pragma unroll
    for (int r = 0; r < 4; ++r)
      av[(grow0 + r) * 1024 + colg] = f2bf(acc[in][r] + bvv);
  }
}

// ---- K4: yb = bf16(AV @ wo + bo)  64x64 tiles, grid (64,16) -> 4 blocks/CU ----
__global__ __launch_bounds__(256) void k_out(
    const unsigned short* __restrict__ av, const unsigned short* __restrict__ wot,
    const float* __restrict__ bo, unsigned short* __restrict__ yb) {
  __shared__ short Asm[64 * 40];
  __shared__ short Bsm[64 * 40];
  int mt = blockIdx.x, nt = blockIdx.y, t = threadIdx.x;
  int lane = t & 63, w = t >> 6;
  int wm = w >> 1, wn = w & 1;
  int l15 = lane & 15, g4 = lane >> 4;
  int lr = t >> 2, lc = (t & 3) << 3;
  const unsigned short* Arp = av + (long)(mt * 64 + lr) * 1024 + lc;
  const unsigned short* Brp = wot + (long)(nt * 64 + lr) * 1024 + lc;
  s16x8 a8 = *(const s16x8*)&Arp[0];
  s16x8 b8 = *(const s16x8*)&Brp[0];
  f32x4 acc[2][2] = {};
  for (int kb = 0; kb < 32; ++kb) {
    __syncthreads();
    *(s16x8*)&Asm[lr * 40 + lc] = a8;
    *(s16x8*)&Bsm[lr * 40 + lc] = b8;
    if (kb + 1 < 32) {
      a8 = *(const s16x8*)&Arp[((kb + 1) << 5)];
      b8 = *(const s16x8*)&Brp[((kb + 1) << 5)];
    }
    __syncthreads();
    s16x8 afr[2], bfr[2];
#pragma unroll
    for (int im = 0; im < 2; ++im)
      afr[im] = *(const s16x8*)&Asm[(wm * 32 + im * 16 + l15) * 40 + (g4 << 3)];
#pragma unroll
    for (int in = 0; in < 2; ++in)
      bfr[in] = *(const s16x8*)&Bsm[(wn * 32 + in * 16 + l15) * 40 + (g4 << 3)];
#pragma unroll
    for (int im = 0; im < 2; ++im)
#pragma unroll
      for (int in = 0; in < 2; ++in)
        acc[im][in] = __builtin_amdgcn_mfma_f32_16x16x32_bf16(afr[im], bfr[in], acc[im][in], 0, 0, 0);
  }
#pragma unroll
  for (int in = 0; in < 2; ++in) {
    int colg = nt * 64 + wn * 32 + in * 16 + l15;
    float bov = bo[colg];
#pragma unroll
    for (int im = 0; im < 2; ++im) {
      long rowg = (long)mt * 64 + wm * 32 + im * 16 + (g4 << 2);
#pragma unroll
      for (int r = 0; r < 4; ++r)
        yb[(rowg + r) * 1024 + colg] = f2bf(acc[im][in][r] + bov);
    }
  }
}

// ---- K5: y = LayerNorm(yb) over last dim (bf16 in, f32 out) ----
__global__ __launch_bounds__(256) void k_ln(
    const unsigned short* __restrict__ yb, const float* __restrict__ gamma,
    const float* __restrict__ beta, float* __restrict__ y) {
  int row = (blockIdx.x << 2) + (threadIdx.x >> 6);
  int lane = threadIdx.x & 63;
  const unsigned short* yr = yb + ((long)row << 10);
  float v[4][4];
  float s = 0.f, s2 = 0.f;
#pragma unroll
  for (int j = 0; j < 4; ++j) {
    s16x4 h4 = *(const s16x4*)&yr[(lane << 2) + (j << 8)];
#pragma unroll
    for (int q = 0; q < 4; ++q) {
      float f = bf2f((unsigned short)h4[q]);
      v[j][q] = f; s += f; s2 += f * f;
    }
  }
#pragma unroll
  for (int d = 1; d < 64; d <<= 1) {
    s += __shfl_xor(s, d, 64);
    s2 += __shfl_xor(s2, d, 64);
  }
  float mu = s * (1.0f / 1024.0f);
  float var = s2 * (1.0f / 1024.0f) - mu * mu;
  float rs = rsqrtf(var + 1e-5f);
  float* yo = y + ((long)row << 10);
#pragma unroll
  for (int j = 0; j < 4; ++j) {
    int f0 = (lane << 2) + (j << 8);
    f32x4 gm = *(const f32x4*)&gamma[f0];
    f32x4 bt = *(const f32x4*)&beta[f0];
    f32x4 o;
#pragma unroll
    for (int q = 0; q < 4; ++q) o[q] = (v[j][q] - mu) * rs * gm[q] + bt[q];
    *(f32x4*)&yo[f0] = o;
  }
}

extern "C" void kernel_launch(void* const* d_in, const int* in_sizes, int n_in,
                              void* d_out, int out_size, void* d_ws, size_t ws_size,
                              hipStream_t stream) {
  (void)in_sizes; (void)n_in; (void)out_size;
  const float* cq    = (const float*)d_in[0];
  const float* G     = (const float*)d_in[1];
  const float* conf  = (const float*)d_in[2];
  const float* wq    = (const float*)d_in[3];
  const float* bq    = (const float*)d_in[4];
  const float* wk    = (const float*)d_in[5];
  const float* bk    = (const float*)d_in[6];
  const float* wv    = (const float*)d_in[7];
  const float* bv    = (const float*)d_in[8];
  const float* wo    = (const float*)d_in[9];
  const float* bo    = (const float*)d_in[10];
  const float* gamma = (const float*)d_in[11];
  const float* beta  = (const float*)d_in[12];

  float* y = (float*)d_out;
  float* alpha = y + 4194304;  // out (8*512*1024) then alpha (8*512*16*16)

  char* p = (char*)d_ws;
  float* qpart = (float*)p;                  p += 8L * 16 * 1024 * 4;   // 512KB
  float* cvec  = (float*)p;                  p += 1024;
  unsigned short* wt   = (unsigned short*)p; p += 8L * 16 * 1024 * 2;   // 256KB
  unsigned short* wvt  = (unsigned short*)p; p += 1024L * 1024 * 2;     // 2MB
  unsigned short* wot  = (unsigned short*)p; p += 1024L * 1024 * 2;     // 2MB
  unsigned short* av   = (unsigned short*)p; p += 4096L * 1024 * 2;     // 8MB
  unsigned short* yb   = (unsigned short*)p; p += 4096L * 1024 * 2;     // 8MB
  unsigned short* gbar = (unsigned short*)p;
  size_t used = (size_t)(p - (char*)d_ws);
  size_t per_b = 512L * 16 * 1024 * 2;  // 16MB of Gbar per batch
  // cap nb at 4: per-chunk working set (G 128MB + gbar 64MB) fits 256MB L3,
  // so k_av reads gbar from L3 and dirty gbar lines die in-cache.
  int nb = 1;
  if (ws_size >= used + 4 * per_b) nb = 4;
  else if (ws_size >= used + 2 * per_b) nb = 2;
  int hstride = nb * 512 * 1024;  // u16 elements per h-plane of gbar

  hipLaunchKernelGGL(k_transq, dim3(576), dim3(256), 0, stream,
                     wv, wo, wvt, wot, cq, wq, qpart);
  hipLaunchKernelGGL(k_wtilde, dim3(32, 8), dim3(256), 0, stream, wk, bk, bq, qpart, wt, cvec);
  for (int c = 0; c < 8; c += nb) {
    hipLaunchKernelGGL(k_scores, dim3(nb * 512), dim3(256), 0, stream,
                       G, conf, wt, cvec, alpha, gbar, c, hstride);
    hipLaunchKernelGGL(k_av, dim3(nb * 16, 16), dim3(256), 0, stream,
                       gbar, wvt, bv, av, c, hstride);
  }
  hipLaunchKernelGGL(k_out, dim3(64, 16), dim3(256), 0, stream, av, wot, bo, yb);
  hipLaunchKernelGGL(k_ln, dim3(1024), dim3(256), 0, stream, yb, gamma, beta, y);
}